// Round 7
// baseline (484.203 us; speedup 1.0000x reference)
//
#include <hip/hip_runtime.h>

// WarpingLayer_3stacks: trilinear scatter-splat (grid_push) of
// intensities = [x*mask, mask] into 128^3, coords = flow + meshgrid.
// Input 384x128x128 f32. Output [1,2,128,128,128] f32.
//
// R1: global f32 atomicAdd ~22G/s -> privatize in LDS.
// R3-R5: three different gather structures all ~190us => model was wrong.
// R6 theory: HIP atomicAdd(float*) lowers to a CAS LOOP (safe-fp-atomics
//   default): ~16 dependent LDS read/cmpxchg round-trips (~240cy) per point
//   => ~64K cycles per wave-iteration observed. Fix: unsafeAtomicAdd ->
//   native ds_add_f32 / global_atomic_add_f32 (fire-and-forget, pipelined).
//   Structure otherwise identical to R5 (single-variable experiment).

#define OS    128
#define OS3   (OS * OS * OS)
#define SRC_D 384
#define SRC_H 128
#define SRC_W 128
#define NSRC  (SRC_D * SRC_H * SRC_W)
#define ZSPLIT 128
#define PLANE_CELLS (OS * OS)

// gather tiling: block owns out[z0:z0+4][y0:y0+4][0:128]
#define TZ 4
#define TY 4
#define HALO 3
#define NJOBS 100          // 10 z-rows x 10 y-rows scan window
#define GITER 7            // ceil(100/16) row-jobs per 512-thr block

#define REG_CAP 512        // per-gather-block record region
#define LCAP    65536      // shared overflow list
#define GPLANE  256        // plane slab groups (1 z-slab each)
#define SLICES  16         // plane reduction fan-in stage 1

// ws layout (bytes)
#define OFF_CNT    0
#define OFF_COUNTS 1024
#define OFF_REGS   8192
#define OFF_LIST   (OFF_REGS + 1024 * REG_CAP * 16)          //  8,396,800
#define OFF_TMP    (OFF_LIST + LCAP * 16)                    //  9,445,376
#define OFF_PART   (16 * 1024 * 1024)
#define WS_NEED    (OFF_PART + GPLANE * 2 * PLANE_CELLS * 4) // 50,331,648

// Native f32 atomic add (ds_add_f32 / global_atomic_add_f32), not CAS loop.
__device__ __forceinline__ void atomAddF(float* p, float v) {
    unsafeAtomicAdd(p, v);
}

// x-dim LDS bank swizzle: float4 lanes stride 4 words -> 8-way conflict.
// XOR bits [1:0] with bits [6:5]: involution, spreads to all 32 banks.
__device__ __forceinline__ int swz(int c) { return c ^ ((c >> 5) & 3); }

// un-permute a float4 loaded from swizzled layout (k = (phys>>5)&3)
__device__ __forceinline__ float4 swz4(float4 v, int k) {
    switch (k & 3) {
        case 1:  return make_float4(v.y, v.x, v.w, v.z);
        case 2:  return make_float4(v.z, v.w, v.x, v.y);
        case 3:  return make_float4(v.w, v.z, v.y, v.x);
        default: return v;
    }
}

// ---------------- gather: source z<128, owns & plain-stores out ------------
__global__ __launch_bounds__(512) void warp_gather(
    const float* __restrict__ x, const float* __restrict__ flow,
    const float* __restrict__ mask, float* __restrict__ out,
    unsigned* __restrict__ gcnt, int* __restrict__ counts,
    int4* __restrict__ regs, int4* __restrict__ list)
{
    __shared__ float acc[2 * TZ * TY * OS];   // 16 KB, x swizzled
    __shared__ int scnt;

    const int tid = threadIdx.x;
    if (tid == 0) scnt = 0;
    {
        float4* a4 = (float4*)acc;
        a4[tid]       = make_float4(0, 0, 0, 0);
        a4[tid + 512] = make_float4(0, 0, 0, 0);
    }
    __syncthreads();

    const int z0 = blockIdx.x * TZ;
    const int y0 = blockIdx.y * TY;
    const int bl = blockIdx.y * gridDim.x + blockIdx.x;
    const int wq = tid & 31;          // w quad: handles w = 4*wq .. +3
    const int slot = tid >> 5;        // 0..15 row-job slot

    const float4* __restrict__ fz4 = (const float4*)flow;
    const float4* __restrict__ fy4 = (const float4*)(flow + NSRC);
    const float4* __restrict__ fx4 = (const float4*)(flow + 2 * NSRC);
    const float4* __restrict__ m4p = (const float4*)mask;
    const float4* __restrict__ x4p = (const float4*)x;

    for (int it = 0; it < GITER; ++it) {
        int j = it * 16 + slot;
        int dz = j / 10, dyy = j - dz * 10;
        int zzr = z0 - HALO + dz;
        int hhr = y0 - HALO + dyy;
        int zz = min(max(zzr, 0), ZSPLIT - 1);
        int hh = min(max(hhr, 0), OS - 1);
        bool vrow = (j < NJOBS) && (zzr >= 0) && (zzr < ZSPLIT) &&
                    (hhr >= 0) && (hhr < OS);
        bool home = vrow && (zzr >= z0) && (zzr < z0 + TZ) &&
                    (hhr >= y0) && (hhr < y0 + TY);

        int idx4 = (((zz << 14) + (hh << 7)) >> 2) + wq;
        float4 vfz = fz4[idx4];       // unconditional clamped-address loads
        float4 vfy = fy4[idx4];
        float4 vfx = fx4[idx4];
        float4 vm  = m4p[idx4];
        float4 vx  = x4p[idx4];

        if (!vrow) continue;

        #pragma unroll
        for (int p = 0; p < 4; ++p) {
            float fzl = ((float*)&vfz)[p];
            float fyl = ((float*)&vfy)[p];
            float gz = fzl + (float)zz;
            float gy = fyl + (float)hh;
            float fzf = floorf(gz), fyf = floorf(gy);
            float ffz = gz - fzf, ffy = gy - fyf;
            int iz0 = (int)fzf, iy0 = (int)fyf;

            int cz0 = min(max(iz0,     0), OS - 1);
            int cz1 = min(max(iz0 + 1, 0), OS - 1);
            int cy0 = min(max(iy0,     0), OS - 1);
            int cy1 = min(max(iy0 + 1, 0), OS - 1);

            bool zin = (cz1 >= z0) && (cz0 < z0 + TZ);
            bool yin = (cy1 >= y0) && (cy0 < y0 + TY);
            if (!home && !(zin && yin)) continue;

            int w = wq * 4 + p;
            float gx = ((float*)&vfx)[p] + (float)w;
            float fxf = floorf(gx);
            float ffx = gx - fxf;
            int ix0 = (int)fxf;
            int cx0 = min(max(ix0,     0), OS - 1);
            int cx1 = min(max(ix0 + 1, 0), OS - 1);

            float m = ((float*)&vm)[p];
            float v = ((float*)&vx)[p] * m;

            #pragma unroll
            for (int d2 = 0; d2 < 2; ++d2) {
                int cz = d2 ? cz1 : cz0;
                float wz = d2 ? ffz : 1.0f - ffz;
                bool nz = (cz - zz <= HALO) && (zz - cz <= HALO);
                int uz = cz - z0;
                #pragma unroll
                for (int e2 = 0; e2 < 2; ++e2) {
                    int cy = e2 ? cy1 : cy0;
                    float wzy = wz * (e2 ? ffy : 1.0f - ffy);
                    bool ny = (cy - hh <= HALO) && (hh - cy <= HALO);
                    int uy = cy - y0;
                    bool nearc = nz && ny;
                    #pragma unroll
                    for (int f2 = 0; f2 < 2; ++f2) {
                        int cx = f2 ? cx1 : cx0;
                        float wgt = wzy * (f2 ? ffx : 1.0f - ffx);
                        if (nearc) {
                            if ((unsigned)uz < TZ && (unsigned)uy < TY) {
                                int off = ((uz * TY + uy) << 7) + swz(cx);
                                atomAddF(&acc[off],                  v * wgt);
                                atomAddF(&acc[(TZ * TY << 7) + off], m * wgt);
                            }
                        } else if (home) {
                            int4 r;
                            r.x = (cz << 14) + (cy << 7) + cx;
                            r.y = __float_as_int(v * wgt);
                            r.z = __float_as_int(m * wgt);
                            r.w = 0;
                            int s = atomicAdd(&scnt, 1);
                            if (s < REG_CAP) regs[bl * REG_CAP + s] = r;
                            else {
                                unsigned g = atomicAdd(gcnt, 1u);
                                if (g < LCAP) list[g] = r;
                            }
                        }
                    }
                }
            }
        }
    }

    __syncthreads();
    if (tid == 0) counts[bl] = min(scnt, REG_CAP);

    // plain-store owned tile (entire volume covered by the tile grid)
    float4* a4 = (float4*)acc;
    #pragma unroll
    for (int s = 0; s < 2; ++s) {
        int jf = tid + s * 512;            // f4 idx 0..1023
        int row = jf >> 5;                 // 0..31
        int ch = row >> 4, uz = (row >> 2) & 3, uy = row & 3;
        int colq = jf & 31;
        int k = (colq >> 3) & 3;
        float4 vv = swz4(a4[jf], k);
        int o4 = (ch * OS3 + ((z0 + uz) << 14) + ((y0 + uy) << 7) + colq * 4) >> 2;
        ((float4*)out)[o4] = vv;
    }
}

// ------- plane: source z>=128, gz>=127 -> z=127 plane partials in LDS -------
__global__ __launch_bounds__(1024) void warp_plane(
    const float* __restrict__ x, const float* __restrict__ flow,
    const float* __restrict__ mask, float* __restrict__ partials,
    unsigned* __restrict__ gcnt, int4* __restrict__ list)
{
    __shared__ float pl[PLANE_CELLS];     // 64 KB, x swizzled

    const int tid = threadIdx.x;
    const int ch = blockIdx.y;
    float4* p4 = (float4*)pl;
    #pragma unroll
    for (int s = 0; s < 4; ++s) p4[tid + s * 1024] = make_float4(0, 0, 0, 0);
    __syncthreads();

    const int z  = ZSPLIT + blockIdx.x;
    const int wq = tid & 31;
    const int r0 = tid >> 5;              // 0..31
    const int lane = tid & 63;

    const float4* __restrict__ fz4 = (const float4*)flow;
    const float4* __restrict__ fy4 = (const float4*)(flow + NSRC);
    const float4* __restrict__ fx4 = (const float4*)(flow + 2 * NSRC);
    const float4* __restrict__ m4p = (const float4*)mask;
    const float4* __restrict__ v4p = (const float4*)(ch ? mask : x);

    for (int s = 0; s < 4; ++s) {
        int row = r0 + s * 32;
        int idx4 = (((z << 14) + (row << 7)) >> 2) + wq;
        float4 vfz = fz4[idx4];
        float4 vfy = fy4[idx4];
        float4 vfx = fx4[idx4];
        float4 vm  = m4p[idx4];
        float4 vv  = v4p[idx4];

        #pragma unroll
        for (int p = 0; p < 4; ++p) {
            float gz = ((float*)&vfz)[p] + (float)z;
            float gy = ((float*)&vfy)[p] + (float)row;
            float gx = ((float*)&vfx)[p] + (float)(wq * 4 + p);
            float m  = ((float*)&vm)[p];
            float vl = ((float*)&vv)[p];

            float fyf = floorf(gy), fxf = floorf(gx);
            float ffy = gy - fyf, ffx = gx - fxf;
            int iy0 = (int)fyf, ix0 = (int)fxf;
            int cy0 = min(max(iy0,     0), OS - 1);
            int cy1 = min(max(iy0 + 1, 0), OS - 1);
            int cx0 = min(max(ix0,     0), OS - 1);
            int cx1 = min(max(ix0 + 1, 0), OS - 1);

            if (gz >= (float)(OS - 1)) {   // both z-corners clamp -> wz sums to 1
                float v = ch ? m : vl * m;
                int sx0 = swz(cx0), sx1 = swz(cx1);
                atomAddF(&pl[(cy0 << 7) + sx0], v * (1.0f - ffy) * (1.0f - ffx));
                atomAddF(&pl[(cy0 << 7) + sx1], v * (1.0f - ffy) * ffx);
                atomAddF(&pl[(cy1 << 7) + sx0], v * ffy * (1.0f - ffx));
                atomAddF(&pl[(cy1 << 7) + sx1], v * ffy * ffx);
            } else if (ch == 0) {
                // rare boundary points (gz<127): append 8 trilinear records,
                // ballot-aggregated counter bump
                float v0 = vl * m;
                float fzf = floorf(gz);
                float ffz = gz - fzf;
                int iz0 = (int)fzf;

                unsigned long long b = __ballot(1);
                int leader = __ffsll((unsigned long long)b) - 1;
                int pre = __popcll(b & ((1ULL << lane) - 1));
                unsigned base = 0;
                if (lane == leader) base = atomicAdd(gcnt, (unsigned)__popcll(b) * 8u);
                base = (unsigned)__shfl((int)base, leader);
                unsigned my = base + (unsigned)pre * 8u;

                int t = 0;
                #pragma unroll
                for (int d2 = 0; d2 < 2; ++d2) {
                    int cz = min(max(iz0 + d2, 0), OS - 1);
                    float wz = d2 ? ffz : 1.0f - ffz;
                    #pragma unroll
                    for (int e2 = 0; e2 < 2; ++e2) {
                        int cy = e2 ? cy1 : cy0;
                        float wzy = wz * (e2 ? ffy : 1.0f - ffy);
                        #pragma unroll
                        for (int f2 = 0; f2 < 2; ++f2) {
                            int cx = f2 ? cx1 : cx0;
                            float wgt = wzy * (f2 ? ffx : 1.0f - ffx);
                            unsigned slot = my + t;
                            if (slot < LCAP) {
                                int4 r;
                                r.x = (cz << 14) + (cy << 7) + cx;
                                r.y = __float_as_int(v0 * wgt);
                                r.z = __float_as_int(m * wgt);
                                r.w = 0;
                                list[slot] = r;
                            }
                            ++t;
                        }
                    }
                }
            }
        }
    }

    __syncthreads();
    float4* dst = (float4*)(partials + (size_t)(blockIdx.x * 2 + ch) * PLANE_CELLS);
    #pragma unroll
    for (int s = 0; s < 4; ++s) dst[tid + s * 1024] = p4[tid + s * 1024];
}

// ---- plane partial reduction, stage 1: 256 -> 16 slices ----
__global__ __launch_bounds__(256) void plane_reduce1(
    const float4* __restrict__ partials, float4* __restrict__ tmp)
{
    int t = blockIdx.x * 256 + threadIdx.x;        // 0..131071
    int slice = t >> 13;
    int rem = t & 8191;
    int ch = rem >> 12;
    int c4 = rem & 4095;
    float4 s = make_float4(0, 0, 0, 0);
    #pragma unroll
    for (int g = 0; g < GPLANE / SLICES; ++g) {
        float4 v = partials[((size_t)((slice * (GPLANE / SLICES) + g) * 2 + ch)) * 4096 + c4];
        s.x += v.x; s.y += v.y; s.z += v.z; s.w += v.w;
    }
    tmp[(size_t)(slice * 2 + ch) * 4096 + c4] = s;
}

// ---- stage 2: 16 -> out (z=127 plane), with swizzle un-permute ----
__global__ __launch_bounds__(256) void plane_reduce2(
    float* __restrict__ out, const float4* __restrict__ tmp)
{
    int t = blockIdx.x * 256 + threadIdx.x;        // 0..8191
    int ch = t >> 12;
    int c4 = t & 4095;
    float4 s = make_float4(0, 0, 0, 0);
    #pragma unroll
    for (int sl = 0; sl < SLICES; ++sl) {
        float4 v = tmp[(size_t)(sl * 2 + ch) * 4096 + c4];
        s.x += v.x; s.y += v.y; s.z += v.z; s.w += v.w;
    }
    int k = (c4 >> 3) & 3;
    float4 w = swz4(s, k);
    int o4 = (ch * OS3 + ((OS - 1) << 14)) / 4 + c4;
    float4 a = ((float4*)out)[o4];
    a.x += w.x; a.y += w.y; a.z += w.z; a.w += w.w;
    ((float4*)out)[o4] = a;
}

// ---- apply overflow records (per-block regions + shared list) ----
__global__ __launch_bounds__(256) void apply_records(
    float* __restrict__ out, const unsigned* __restrict__ gcnt,
    const int* __restrict__ counts, const int4* __restrict__ regs,
    const int4* __restrict__ list)
{
    int b = blockIdx.x;
    if (b < 1024) {
        int n = counts[b];
        const int4* r = regs + (size_t)b * REG_CAP;
        for (int i = threadIdx.x; i < n; i += 256) {
            int4 q = r[i];
            atomAddF(out + q.x,       __int_as_float(q.y));
            atomAddF(out + OS3 + q.x, __int_as_float(q.z));
        }
    } else {
        unsigned n = *gcnt;
        if (n > LCAP) n = LCAP;
        for (unsigned i = (unsigned)(b - 1024) * 256 + threadIdx.x; i < n; i += 8 * 256) {
            int4 q = list[i];
            atomAddF(out + q.x,       __int_as_float(q.y));
            atomAddF(out + OS3 + q.x, __int_as_float(q.z));
        }
    }
}

// ---------------- fallback (ws too small): naive merged scatter ------------
__global__ __launch_bounds__(256) void warp_push_naive(
    const float* __restrict__ x, const float* __restrict__ flow,
    const float* __restrict__ mask, float* __restrict__ out, int N)
{
    int idx = blockIdx.x * blockDim.x + threadIdx.x;
    if (idx >= N) return;
    int w = idx & 127, h = (idx >> 7) & 127, z = idx >> 14;
    float gz = flow[idx] + (float)z;
    float gy = flow[N + idx] + (float)h;
    float gx = flow[2 * N + idx] + (float)w;
    float m = mask[idx];
    float v0 = x[idx] * m;
    float fz0 = floorf(gz), fy0 = floorf(gy), fx0 = floorf(gx);
    float fz = gz - fz0, fy = gy - fy0, fx = gx - fx0;
    int iz0 = (int)fz0, iy0 = (int)fy0, ix0 = (int)fx0;
    #pragma unroll
    for (int dz = 0; dz < 2; ++dz) {
        int cz = min(max(iz0 + dz, 0), OS - 1);
        float wz = dz ? fz : 1.0f - fz;
        #pragma unroll
        for (int dy = 0; dy < 2; ++dy) {
            int cy = min(max(iy0 + dy, 0), OS - 1);
            float wzy = wz * (dy ? fy : 1.0f - fy);
            #pragma unroll
            for (int dx = 0; dx < 2; ++dx) {
                int cx = min(max(ix0 + dx, 0), OS - 1);
                float wgt = wzy * (dx ? fx : 1.0f - fx);
                int o = (cz << 14) + (cy << 7) + cx;
                atomAddF(out + o,       v0 * wgt);
                atomAddF(out + OS3 + o, m * wgt);
            }
        }
    }
}

extern "C" void kernel_launch(void* const* d_in, const int* in_sizes, int n_in,
                              void* d_out, int out_size, void* d_ws, size_t ws_size,
                              hipStream_t stream) {
    (void)in_sizes; (void)n_in; (void)out_size;
    const float* x    = (const float*)d_in[0];
    const float* flow = (const float*)d_in[1];
    const float* mask = (const float*)d_in[2];
    float* out = (float*)d_out;

    if (ws_size >= (size_t)WS_NEED) {
        char* wsb = (char*)d_ws;
        unsigned* gcnt = (unsigned*)(wsb + OFF_CNT);
        int* counts    = (int*)(wsb + OFF_COUNTS);
        int4* regs     = (int4*)(wsb + OFF_REGS);
        int4* list     = (int4*)(wsb + OFF_LIST);
        float4* tmp    = (float4*)(wsb + OFF_TMP);
        float* parts   = (float*)(wsb + OFF_PART);

        hipMemsetAsync(d_ws, 0, 64, stream);   // zero list counter

        warp_gather<<<dim3(OS / TZ, OS / TY), 512, 0, stream>>>(
            x, flow, mask, out, gcnt, counts, regs, list);
        warp_plane<<<dim3(GPLANE, 2), 1024, 0, stream>>>(
            x, flow, mask, parts, gcnt, list);
        plane_reduce1<<<512, 256, 0, stream>>>((const float4*)parts, tmp);
        plane_reduce2<<<32, 256, 0, stream>>>(out, (const float4*)tmp);
        apply_records<<<1024 + 8, 256, 0, stream>>>(out, gcnt, counts, regs, list);
    } else {
        hipMemsetAsync(d_out, 0, (size_t)2 * OS3 * sizeof(float), stream);
        warp_push_naive<<<NSRC / 256, 256, 0, stream>>>(x, flow, mask, out, NSRC);
    }
}

// Round 8
// 247.539 us; speedup vs baseline: 1.9561x; 1.9561x over previous
//
#include <hip/hip_runtime.h>

// WarpingLayer_3stacks: trilinear scatter-splat (grid_push) of
// intensities = [x*mask, mask] into 128^3, coords = flow + meshgrid.
// Input 384x128x128 f32. Output [1,2,128,128,128] f32.
//
// R1: global f32 atomicAdd ~22G/s -> privatize in LDS.
// R3-R6: four structures all ~187us. Invariant = LDS lane-atomic count:
//   446K cy / 131K lane-atomics/CU ~= 3.4 cy/lane-atomic => the LDS atomic
//   unit is the wall. R7: HALVE the atomic count: pack (v,m) channels as
//   32.18 fixed-point fields of ONE u64 and use native ds_add_u64.
//   Low field (m>=0) can never carry into high field (cell sums < 2^27).

#define OS    128
#define OS3   (OS * OS * OS)
#define SRC_D 384
#define SRC_H 128
#define SRC_W 128
#define NSRC  (SRC_D * SRC_H * SRC_W)
#define ZSPLIT 128
#define PLANE_CELLS (OS * OS)

// gather tiling: block owns out[z0:z0+4][y0:y0+4][0:128]
#define TZ 4
#define TY 4
#define HALO 3
#define NJOBS 100          // 10 z-rows x 10 y-rows scan window
#define GITER 7            // ceil(100/16) row-jobs per 512-thr block

#define REG_CAP 512        // per-gather-block record region
#define LCAP    65536      // shared overflow list
#define GPLANE  256        // plane z-slabs
#define SLICES  16         // plane reduction fan-in stage 1

// ws layout (bytes)
#define OFF_CNT    0
#define OFF_COUNTS 1024
#define OFF_REGS   8192
#define OFF_LIST   (OFF_REGS + 1024 * REG_CAP * 16)          //  8,396,800
#define OFF_TMP    (OFF_LIST + LCAP * 16)                    //  9,445,376
#define OFF_PART   (16 * 1024 * 1024)
#define WS_NEED    (OFF_PART + GPLANE * 2 * PLANE_CELLS * 4) // 50,331,648

#define S_FIX   262144.0f            // 2^18
#define INV_FIX (1.0f / 262144.0f)

// pack (v, m) as [v:int32.18 | m:uint32.18]; m >= 0 so low field never
// carries into high (cell sums bounded << 2^31). u64 add == two field adds.
__device__ __forceinline__ unsigned long long pack2(float v, float m) {
    int vi = (int)rintf(v * S_FIX);
    int mi = (int)rintf(m * S_FIX);
    return ((unsigned long long)(unsigned)vi << 32) | (unsigned long long)(unsigned)mi;
}

// u64-cell bank swizzle: 32 lanes stride-4 columns -> exactly 2 lanes per
// u64-bank-pair after XOR of bits[2:0] with bits[6:4]. Involution.
__device__ __forceinline__ int swzq(int c) { return c ^ ((c >> 4) & 7); }

// native global f32 atomic for the rare record-apply / fallback paths
__device__ __forceinline__ void atomAddF(float* p, float v) {
    unsafeAtomicAdd(p, v);
}

// ---------------- gather: source z<128, owns & plain-stores out ------------
// grid (32, 32) = 1024 blocks x 512 thr. Block owns out[z0:z0+4][y0:y0+4][:].
__global__ __launch_bounds__(512) void warp_gather(
    const float* __restrict__ x, const float* __restrict__ flow,
    const float* __restrict__ mask, float* __restrict__ out,
    unsigned* __restrict__ gcnt, int* __restrict__ counts,
    int4* __restrict__ regs, int4* __restrict__ list)
{
    __shared__ unsigned long long tile[TZ * TY * OS];   // 16 KB packed cells
    __shared__ int scnt;

    const int tid = threadIdx.x;
    if (tid == 0) scnt = 0;
    #pragma unroll
    for (int s = 0; s < (TZ * TY * OS) / 512; ++s)
        tile[tid + s * 512] = 0ull;
    __syncthreads();

    const int z0 = blockIdx.x * TZ;
    const int y0 = blockIdx.y * TY;
    const int bl = blockIdx.y * gridDim.x + blockIdx.x;
    const int wq = tid & 31;          // w quad: handles w = 4*wq .. +3
    const int slot = tid >> 5;        // 0..15 row-job slot

    const float4* __restrict__ fz4 = (const float4*)flow;
    const float4* __restrict__ fy4 = (const float4*)(flow + NSRC);
    const float4* __restrict__ fx4 = (const float4*)(flow + 2 * NSRC);
    const float4* __restrict__ m4p = (const float4*)mask;
    const float4* __restrict__ x4p = (const float4*)x;

    for (int it = 0; it < GITER; ++it) {
        int j = it * 16 + slot;
        int dz = j / 10, dyy = j - dz * 10;
        int zzr = z0 - HALO + dz;
        int hhr = y0 - HALO + dyy;
        int zz = min(max(zzr, 0), ZSPLIT - 1);
        int hh = min(max(hhr, 0), OS - 1);
        bool vrow = (j < NJOBS) && (zzr >= 0) && (zzr < ZSPLIT) &&
                    (hhr >= 0) && (hhr < OS);
        bool home = vrow && (zzr >= z0) && (zzr < z0 + TZ) &&
                    (hhr >= y0) && (hhr < y0 + TY);

        int idx4 = (((zz << 14) + (hh << 7)) >> 2) + wq;
        float4 vfz = fz4[idx4];       // unconditional clamped-address loads
        float4 vfy = fy4[idx4];
        float4 vfx = fx4[idx4];
        float4 vm  = m4p[idx4];
        float4 vx  = x4p[idx4];

        if (!vrow) continue;

        #pragma unroll
        for (int p = 0; p < 4; ++p) {
            float fzl = ((float*)&vfz)[p];
            float fyl = ((float*)&vfy)[p];
            float gz = fzl + (float)zz;
            float gy = fyl + (float)hh;
            float fzf = floorf(gz), fyf = floorf(gy);
            float ffz = gz - fzf, ffy = gy - fyf;
            int iz0 = (int)fzf, iy0 = (int)fyf;

            int cz0 = min(max(iz0,     0), OS - 1);
            int cz1 = min(max(iz0 + 1, 0), OS - 1);
            int cy0 = min(max(iy0,     0), OS - 1);
            int cy1 = min(max(iy0 + 1, 0), OS - 1);

            bool zin = (cz1 >= z0) && (cz0 < z0 + TZ);
            bool yin = (cy1 >= y0) && (cy0 < y0 + TY);
            if (!home && !(zin && yin)) continue;

            int w = wq * 4 + p;
            float gx = ((float*)&vfx)[p] + (float)w;
            float fxf = floorf(gx);
            float ffx = gx - fxf;
            int ix0 = (int)fxf;
            int cx0 = min(max(ix0,     0), OS - 1);
            int cx1 = min(max(ix0 + 1, 0), OS - 1);

            float m = ((float*)&vm)[p];
            float v = ((float*)&vx)[p] * m;

            #pragma unroll
            for (int d2 = 0; d2 < 2; ++d2) {
                int cz = d2 ? cz1 : cz0;
                float wz = d2 ? ffz : 1.0f - ffz;
                bool nz = (cz - zz <= HALO) && (zz - cz <= HALO);
                int uz = cz - z0;
                #pragma unroll
                for (int e2 = 0; e2 < 2; ++e2) {
                    int cy = e2 ? cy1 : cy0;
                    float wzy = wz * (e2 ? ffy : 1.0f - ffy);
                    bool ny = (cy - hh <= HALO) && (hh - cy <= HALO);
                    int uy = cy - y0;
                    bool nearc = nz && ny;
                    #pragma unroll
                    for (int f2 = 0; f2 < 2; ++f2) {
                        int cx = f2 ? cx1 : cx0;
                        float wgt = wzy * (f2 ? ffx : 1.0f - ffx);
                        if (nearc) {
                            if ((unsigned)uz < TZ && (unsigned)uy < TY) {
                                int off = ((uz * TY + uy) << 7) + swzq(cx);
                                atomicAdd(&tile[off], pack2(v * wgt, m * wgt));
                            }
                        } else if (home) {
                            int4 r;
                            r.x = (cz << 14) + (cy << 7) + cx;
                            r.y = __float_as_int(v * wgt);
                            r.z = __float_as_int(m * wgt);
                            r.w = 0;
                            int s = atomicAdd(&scnt, 1);
                            if (s < REG_CAP) regs[bl * REG_CAP + s] = r;
                            else {
                                unsigned g = atomicAdd(gcnt, 1u);
                                if (g < LCAP) list[g] = r;
                            }
                        }
                    }
                }
            }
        }
    }

    __syncthreads();
    if (tid == 0) counts[bl] = min(scnt, REG_CAP);

    // unpack + plain-store owned tile (tile grid partitions the volume)
    for (int i = tid; i < TZ * TY * OS; i += 512) {
        int row = i >> 7;              // uz*TY + uy
        int c   = i & 127;
        unsigned long long cell = tile[(row << 7) | swzq(c)];
        float v = (float)(int)(cell >> 32) * INV_FIX;
        float m = (float)(int)(unsigned)cell * INV_FIX;
        int uz = row >> 2, uy = row & 3;
        int o = ((z0 + uz) << 14) + ((y0 + uy) << 7) + c;
        out[o]       = v;
        out[OS3 + o] = m;
    }
}

// ------- plane: source z>=128, gz>=127 -> z=127 plane, half-plane u64 ------
// grid (256 slabs, 2 y-halves) x 1024 thr. Block accumulates BOTH channels
// (packed) for output rows [64H, 64H+64). Scans source rows within +-5.
__global__ __launch_bounds__(1024) void warp_plane(
    const float* __restrict__ x, const float* __restrict__ flow,
    const float* __restrict__ mask, float* __restrict__ partials,
    unsigned* __restrict__ gcnt, int4* __restrict__ list)
{
    __shared__ unsigned long long hp[64 * OS];   // 64 KB packed half-plane

    const int tid = threadIdx.x;
    const int g   = blockIdx.x;
    const int H   = blockIdx.y;
    #pragma unroll
    for (int s = 0; s < (64 * OS) / 1024; ++s)
        hp[tid + s * 1024] = 0ull;
    __syncthreads();

    const int z     = ZSPLIT + g;
    const int ybase = H << 6;
    const int rlo   = max(0, ybase - 5);
    const int rhi   = min(OS, ybase + 64 + 5);
    const int wq    = tid & 31;
    const int rs    = tid >> 5;            // 0..31

    const float4* __restrict__ fz4 = (const float4*)flow;
    const float4* __restrict__ fy4 = (const float4*)(flow + NSRC);
    const float4* __restrict__ fx4 = (const float4*)(flow + 2 * NSRC);
    const float4* __restrict__ m4p = (const float4*)mask;
    const float4* __restrict__ x4p = (const float4*)x;

    for (int rb = 0; rb < 3; ++rb) {
        int r = rlo + rb * 32 + rs;
        bool valid = r < rhi;
        int rc = min(r, OS - 1);
        int idx4 = (((z << 14) + (rc << 7)) >> 2) + wq;
        float4 vfz = fz4[idx4];
        float4 vfy = fy4[idx4];
        float4 vfx = fx4[idx4];
        float4 vm  = m4p[idx4];
        float4 vx  = x4p[idx4];
        if (!valid) continue;
        bool homeRow = ((r >> 6) == H);

        #pragma unroll
        for (int p = 0; p < 4; ++p) {
            int w = wq * 4 + p;
            float gz = ((float*)&vfz)[p] + (float)z;
            float gy = ((float*)&vfy)[p] + (float)r;
            float gx = ((float*)&vfx)[p] + (float)w;
            float m  = ((float*)&vm)[p];
            float v  = ((float*)&vx)[p] * m;

            float fyf = floorf(gy), fxf = floorf(gx);
            float ffy = gy - fyf, ffx = gx - fxf;
            int iy0 = (int)fyf, ix0 = (int)fxf;
            int cy0 = min(max(iy0,     0), OS - 1);
            int cy1 = min(max(iy0 + 1, 0), OS - 1);
            int cx0 = min(max(ix0,     0), OS - 1);
            int cx1 = min(max(ix0 + 1, 0), OS - 1);
            int sx0 = swzq(cx0), sx1 = swzq(cx1);

            if (gz >= (float)(OS - 1)) {   // both z-corners clamp: wz sums to 1
                float wy0 = 1.0f - ffy, wy1 = ffy;
                float wx0 = 1.0f - ffx, wx1 = ffx;

                int u0 = cy0 - ybase;
                bool n0 = (cy0 - r <= 5) && (r - cy0 <= 5);
                if (n0 && (unsigned)u0 < 64u) {
                    unsigned long long* row = &hp[u0 << 7];
                    atomicAdd(&row[sx0], pack2(v * wy0 * wx0, m * wy0 * wx0));
                    atomicAdd(&row[sx1], pack2(v * wy0 * wx1, m * wy0 * wx1));
                }
                int u1 = cy1 - ybase;
                bool n1 = (cy1 - r <= 5) && (r - cy1 <= 5);
                if (n1 && (unsigned)u1 < 64u) {
                    unsigned long long* row = &hp[u1 << 7];
                    atomicAdd(&row[sx0], pack2(v * wy1 * wx0, m * wy1 * wx0));
                    atomicAdd(&row[sx1], pack2(v * wy1 * wx1, m * wy1 * wx1));
                }
                // far-y corners (|flow_y|>5, ~never): home row routes records
                if (homeRow && (!n0 || !n1)) {
                    const int pb = (OS - 1) << 14;
                    #pragma unroll
                    for (int e2 = 0; e2 < 2; ++e2) {
                        bool far = e2 ? !n1 : !n0;
                        if (!far) continue;
                        int cy = e2 ? cy1 : cy0;
                        float wy = e2 ? wy1 : wy0;
                        unsigned base = atomicAdd(gcnt, 2u);
                        #pragma unroll
                        for (int f2 = 0; f2 < 2; ++f2) {
                            unsigned slt = base + f2;
                            if (slt < LCAP) {
                                float wgt = wy * (f2 ? wx1 : wx0);
                                int4 q;
                                q.x = pb + (cy << 7) + (f2 ? cx1 : cx0);
                                q.y = __float_as_int(v * wgt);
                                q.z = __float_as_int(m * wgt);
                                q.w = 0;
                                list[slt] = q;
                            }
                        }
                    }
                }
            } else if (homeRow) {
                // rare boundary (z in [128,~131) with big negative flow_z):
                // full trilinear via 8 records
                float fzf = floorf(gz);
                float ffz = gz - fzf;
                int iz0 = (int)fzf;
                unsigned base = atomicAdd(gcnt, 8u);
                int t = 0;
                #pragma unroll
                for (int d2 = 0; d2 < 2; ++d2) {
                    int cz = min(max(iz0 + d2, 0), OS - 1);
                    float wz = d2 ? ffz : 1.0f - ffz;
                    #pragma unroll
                    for (int e2 = 0; e2 < 2; ++e2) {
                        int cy = e2 ? cy1 : cy0;
                        float wzy = wz * (e2 ? ffy : 1.0f - ffy);
                        #pragma unroll
                        for (int f2 = 0; f2 < 2; ++f2) {
                            int cx = f2 ? cx1 : cx0;
                            float wgt = wzy * (f2 ? ffx : 1.0f - ffx);
                            unsigned slt = base + t;
                            if (slt < LCAP) {
                                int4 q;
                                q.x = (cz << 14) + (cy << 7) + cx;
                                q.y = __float_as_int(v * wgt);
                                q.z = __float_as_int(m * wgt);
                                q.w = 0;
                                list[slt] = q;
                            }
                            ++t;
                        }
                    }
                }
            }
        }
    }

    __syncthreads();

    // unpack + store half-plane partials (un-swizzled f32, both channels)
    float* dst0 = partials + (size_t)g * 2 * PLANE_CELLS;   // ch0
    float* dst1 = dst0 + PLANE_CELLS;                        // ch1
    for (int i = tid; i < 64 * OS; i += 1024) {
        int row = i >> 7, c = i & 127;
        unsigned long long cell = hp[(row << 7) | swzq(c)];
        float v = (float)(int)(cell >> 32) * INV_FIX;
        float m = (float)(int)(unsigned)cell * INV_FIX;
        int o = ((ybase + row) << 7) + c;
        dst0[o] = v;
        dst1[o] = m;
    }
}

// ---- plane partial reduction, stage 1: 256 -> 16 slices ----
__global__ __launch_bounds__(256) void plane_reduce1(
    const float4* __restrict__ partials, float4* __restrict__ tmp)
{
    int t = blockIdx.x * 256 + threadIdx.x;        // 0..131071
    int slice = t >> 13;
    int rem = t & 8191;
    int ch = rem >> 12;
    int c4 = rem & 4095;
    float4 s = make_float4(0, 0, 0, 0);
    #pragma unroll
    for (int g = 0; g < GPLANE / SLICES; ++g) {
        float4 v = partials[((size_t)((slice * (GPLANE / SLICES) + g) * 2 + ch)) * 4096 + c4];
        s.x += v.x; s.y += v.y; s.z += v.z; s.w += v.w;
    }
    tmp[(size_t)(slice * 2 + ch) * 4096 + c4] = s;
}

// ---- stage 2: 16 -> out (z=127 plane) ----
__global__ __launch_bounds__(256) void plane_reduce2(
    float* __restrict__ out, const float4* __restrict__ tmp)
{
    int t = blockIdx.x * 256 + threadIdx.x;        // 0..8191
    int ch = t >> 12;
    int c4 = t & 4095;
    float4 s = make_float4(0, 0, 0, 0);
    #pragma unroll
    for (int sl = 0; sl < SLICES; ++sl) {
        float4 v = tmp[(size_t)(sl * 2 + ch) * 4096 + c4];
        s.x += v.x; s.y += v.y; s.z += v.z; s.w += v.w;
    }
    int o4 = (ch * OS3 + ((OS - 1) << 14)) / 4 + c4;
    float4 a = ((float4*)out)[o4];
    a.x += s.x; a.y += s.y; a.z += s.z; a.w += s.w;
    ((float4*)out)[o4] = a;
}

// ---- apply overflow records (per-block regions + shared list) ----
__global__ __launch_bounds__(256) void apply_records(
    float* __restrict__ out, const unsigned* __restrict__ gcnt,
    const int* __restrict__ counts, const int4* __restrict__ regs,
    const int4* __restrict__ list)
{
    int b = blockIdx.x;
    if (b < 1024) {
        int n = counts[b];
        const int4* r = regs + (size_t)b * REG_CAP;
        for (int i = threadIdx.x; i < n; i += 256) {
            int4 q = r[i];
            atomAddF(out + q.x,       __int_as_float(q.y));
            atomAddF(out + OS3 + q.x, __int_as_float(q.z));
        }
    } else {
        unsigned n = *gcnt;
        if (n > LCAP) n = LCAP;
        for (unsigned i = (unsigned)(b - 1024) * 256 + threadIdx.x; i < n; i += 8 * 256) {
            int4 q = list[i];
            atomAddF(out + q.x,       __int_as_float(q.y));
            atomAddF(out + OS3 + q.x, __int_as_float(q.z));
        }
    }
}

// ---------------- fallback (ws too small): naive merged scatter ------------
__global__ __launch_bounds__(256) void warp_push_naive(
    const float* __restrict__ x, const float* __restrict__ flow,
    const float* __restrict__ mask, float* __restrict__ out, int N)
{
    int idx = blockIdx.x * blockDim.x + threadIdx.x;
    if (idx >= N) return;
    int w = idx & 127, h = (idx >> 7) & 127, z = idx >> 14;
    float gz = flow[idx] + (float)z;
    float gy = flow[N + idx] + (float)h;
    float gx = flow[2 * N + idx] + (float)w;
    float m = mask[idx];
    float v0 = x[idx] * m;
    float fz0 = floorf(gz), fy0 = floorf(gy), fx0 = floorf(gx);
    float fz = gz - fz0, fy = gy - fy0, fx = gx - fx0;
    int iz0 = (int)fz0, iy0 = (int)fy0, ix0 = (int)fx0;
    #pragma unroll
    for (int dz = 0; dz < 2; ++dz) {
        int cz = min(max(iz0 + dz, 0), OS - 1);
        float wz = dz ? fz : 1.0f - fz;
        #pragma unroll
        for (int dy = 0; dy < 2; ++dy) {
            int cy = min(max(iy0 + dy, 0), OS - 1);
            float wzy = wz * (dy ? fy : 1.0f - fy);
            #pragma unroll
            for (int dx = 0; dx < 2; ++dx) {
                int cx = min(max(ix0 + dx, 0), OS - 1);
                float wgt = wzy * (dx ? fx : 1.0f - fx);
                int o = (cz << 14) + (cy << 7) + cx;
                atomAddF(out + o,       v0 * wgt);
                atomAddF(out + OS3 + o, m * wgt);
            }
        }
    }
}

extern "C" void kernel_launch(void* const* d_in, const int* in_sizes, int n_in,
                              void* d_out, int out_size, void* d_ws, size_t ws_size,
                              hipStream_t stream) {
    (void)in_sizes; (void)n_in; (void)out_size;
    const float* x    = (const float*)d_in[0];
    const float* flow = (const float*)d_in[1];
    const float* mask = (const float*)d_in[2];
    float* out = (float*)d_out;

    if (ws_size >= (size_t)WS_NEED) {
        char* wsb = (char*)d_ws;
        unsigned* gcnt = (unsigned*)(wsb + OFF_CNT);
        int* counts    = (int*)(wsb + OFF_COUNTS);
        int4* regs     = (int4*)(wsb + OFF_REGS);
        int4* list     = (int4*)(wsb + OFF_LIST);
        float4* tmp    = (float4*)(wsb + OFF_TMP);
        float* parts   = (float*)(wsb + OFF_PART);

        hipMemsetAsync(d_ws, 0, 64, stream);   // zero list counter

        warp_gather<<<dim3(OS / TZ, OS / TY), 512, 0, stream>>>(
            x, flow, mask, out, gcnt, counts, regs, list);
        warp_plane<<<dim3(GPLANE, 2), 1024, 0, stream>>>(
            x, flow, mask, parts, gcnt, list);
        plane_reduce1<<<512, 256, 0, stream>>>((const float4*)parts, tmp);
        plane_reduce2<<<32, 256, 0, stream>>>(out, (const float4*)tmp);
        apply_records<<<1024 + 8, 256, 0, stream>>>(out, gcnt, counts, regs, list);
    } else {
        hipMemsetAsync(d_out, 0, (size_t)2 * OS3 * sizeof(float), stream);
        warp_push_naive<<<NSRC / 256, 256, 0, stream>>>(x, flow, mask, out, NSRC);
    }
}

// Round 9
// 205.534 us; speedup vs baseline: 2.3558x; 1.2044x over previous
//
#include <hip/hip_runtime.h>

// WarpingLayer_3stacks: trilinear scatter-splat (grid_push) of
// intensities = [x*mask, mask] into 128^3, coords = flow + meshgrid.
// Input 384x128x128 f32. Output [1,2,128,128,128] f32.
//
// R1: global f32 atomicAdd is the wall -> privatize in LDS.
// R3-R6: structure-invariant ~187us => LDS lane-atomic throughput (~3.4cy)
//        is the pipe. R7/R8: pack both channels in one u64 (ds_add_u64,
//        fixed-point 32.18 fields, no cross-field carries) -> 247us.
// R9: kernel sum ~140us but total 247 => ~100us inter-dispatch overhead.
//     Fuse: [gather + plane] one kernel (512thr; plane = 32KB quarter-plane,
//     2 slabs x 4 quarters x 128 groups -> partials 32->16MB), and
//     [reduce2 + apply_records] one kernel (atomic +=). 4 dispatches total.

#define OS    128
#define OS3   (OS * OS * OS)
#define SRC_D 384
#define SRC_H 128
#define SRC_W 128
#define NSRC  (SRC_D * SRC_H * SRC_W)
#define ZSPLIT 128
#define PLANE_CELLS (OS * OS)

// gather tiling: block owns out[z0:z0+4][y0:y0+4][0:128]
#define TZ 4
#define TY 4
#define HALO 3
#define NJOBS 100          // 10 z-rows x 10 y-rows scan window
#define GITER 7            // ceil(100/16) row-jobs per 512-thr block
#define GBLK  1024         // gather blocks (32 x 32)

// plane tiling: quarter-plane (32 rows) per block, 2 z-slabs per group
#define PGROUPS 128        // z-groups (2 slabs each)
#define PSPB    2
#define PBLK    (PGROUPS * 4)   // 512 plane blocks
#define SLICES  16         // reduction fan-in stage 1 (128 -> 16)

#define REG_CAP 512        // per-gather-block record region
#define LCAP    65536      // shared overflow list

// ws layout (bytes)
#define OFF_CNT    0
#define OFF_COUNTS 1024
#define OFF_REGS   8192
#define OFF_LIST   (OFF_REGS + GBLK * REG_CAP * 16)          //  8,396,800
#define OFF_TMP    (OFF_LIST + LCAP * 16)                    //  9,445,376
#define OFF_PART   (16 * 1024 * 1024)
#define WS_NEED    (OFF_PART + PGROUPS * 2 * PLANE_CELLS * 4) // 32 MB

#define S_FIX   262144.0f            // 2^18
#define INV_FIX (1.0f / 262144.0f)

// pack (v, m) as [v:int32.18 | m:uint32.18]; m >= 0 and cell m-sums < 2^31,
// so the low field never carries into the high field; v's signed wraparound
// stays inside the top 32 bits (mod 2^64 add).
__device__ __forceinline__ unsigned long long pack2(float v, float m) {
    int vi = (int)rintf(v * S_FIX);
    int mi = (int)rintf(m * S_FIX);
    return ((unsigned long long)(unsigned)vi << 32) | (unsigned long long)(unsigned)mi;
}

// u64-cell bank swizzle (involution): spreads stride-4 column access.
__device__ __forceinline__ int swzq(int c) { return c ^ ((c >> 4) & 7); }

__device__ __forceinline__ void atomAddF(float* p, float v) {
    unsafeAtomicAdd(p, v);
}

// =================== K1: fused gather (z<128) + plane (z>=128) =============
// grid.x = GBLK + PBLK, 512 threads. LDS: 32 KB shared between the two roles.
__global__ __launch_bounds__(512) void warp_fused(
    const float* __restrict__ x, const float* __restrict__ flow,
    const float* __restrict__ mask, float* __restrict__ out,
    float* __restrict__ partials,
    unsigned* __restrict__ gcnt, int* __restrict__ counts,
    int4* __restrict__ regs, int4* __restrict__ list)
{
    __shared__ unsigned long long sh[4096];   // 32 KB
    __shared__ int scnt;

    const int tid = threadIdx.x;
    const int b = blockIdx.x;

    const float4* __restrict__ fz4 = (const float4*)flow;
    const float4* __restrict__ fy4 = (const float4*)(flow + NSRC);
    const float4* __restrict__ fx4 = (const float4*)(flow + 2 * NSRC);
    const float4* __restrict__ m4p = (const float4*)mask;
    const float4* __restrict__ x4p = (const float4*)x;

    if (b < GBLK) {
        // ---------------- gather role ----------------
        if (tid == 0) scnt = 0;
        #pragma unroll
        for (int s = 0; s < (TZ * TY * OS) / 512; ++s)
            sh[tid + s * 512] = 0ull;
        __syncthreads();

        const int z0 = (b & 31) * TZ;
        const int y0 = (b >> 5) * TY;
        const int wq = tid & 31;
        const int slot = tid >> 5;

        for (int it = 0; it < GITER; ++it) {
            int j = it * 16 + slot;
            int dz = j / 10, dyy = j - dz * 10;
            int zzr = z0 - HALO + dz;
            int hhr = y0 - HALO + dyy;
            int zz = min(max(zzr, 0), ZSPLIT - 1);
            int hh = min(max(hhr, 0), OS - 1);
            bool vrow = (j < NJOBS) && (zzr >= 0) && (zzr < ZSPLIT) &&
                        (hhr >= 0) && (hhr < OS);
            bool home = vrow && (zzr >= z0) && (zzr < z0 + TZ) &&
                        (hhr >= y0) && (hhr < y0 + TY);

            int idx4 = (((zz << 14) + (hh << 7)) >> 2) + wq;
            float4 vfz = fz4[idx4];
            float4 vfy = fy4[idx4];
            float4 vfx = fx4[idx4];
            float4 vm  = m4p[idx4];
            float4 vx  = x4p[idx4];

            if (!vrow) continue;

            #pragma unroll
            for (int p = 0; p < 4; ++p) {
                float gz = ((float*)&vfz)[p] + (float)zz;
                float gy = ((float*)&vfy)[p] + (float)hh;
                float fzf = floorf(gz), fyf = floorf(gy);
                float ffz = gz - fzf, ffy = gy - fyf;
                int iz0 = (int)fzf, iy0 = (int)fyf;

                int cz0 = min(max(iz0,     0), OS - 1);
                int cz1 = min(max(iz0 + 1, 0), OS - 1);
                int cy0 = min(max(iy0,     0), OS - 1);
                int cy1 = min(max(iy0 + 1, 0), OS - 1);

                bool zin = (cz1 >= z0) && (cz0 < z0 + TZ);
                bool yin = (cy1 >= y0) && (cy0 < y0 + TY);
                if (!home && !(zin && yin)) continue;

                int w = wq * 4 + p;
                float gx = ((float*)&vfx)[p] + (float)w;
                float fxf = floorf(gx);
                float ffx = gx - fxf;
                int ix0 = (int)fxf;
                int cx0 = min(max(ix0,     0), OS - 1);
                int cx1 = min(max(ix0 + 1, 0), OS - 1);

                float m = ((float*)&vm)[p];
                float v = ((float*)&vx)[p] * m;

                #pragma unroll
                for (int d2 = 0; d2 < 2; ++d2) {
                    int cz = d2 ? cz1 : cz0;
                    float wz = d2 ? ffz : 1.0f - ffz;
                    bool nz = (cz - zz <= HALO) && (zz - cz <= HALO);
                    int uz = cz - z0;
                    #pragma unroll
                    for (int e2 = 0; e2 < 2; ++e2) {
                        int cy = e2 ? cy1 : cy0;
                        float wzy = wz * (e2 ? ffy : 1.0f - ffy);
                        bool ny = (cy - hh <= HALO) && (hh - cy <= HALO);
                        int uy = cy - y0;
                        bool nearc = nz && ny;
                        #pragma unroll
                        for (int f2 = 0; f2 < 2; ++f2) {
                            int cx = f2 ? cx1 : cx0;
                            float wgt = wzy * (f2 ? ffx : 1.0f - ffx);
                            if (nearc) {
                                if ((unsigned)uz < TZ && (unsigned)uy < TY) {
                                    int off = ((uz * TY + uy) << 7) + swzq(cx);
                                    atomicAdd(&sh[off], pack2(v * wgt, m * wgt));
                                }
                            } else if (home) {
                                int4 r;
                                r.x = (cz << 14) + (cy << 7) + cx;
                                r.y = __float_as_int(v * wgt);
                                r.z = __float_as_int(m * wgt);
                                r.w = 0;
                                int s = atomicAdd(&scnt, 1);
                                if (s < REG_CAP) regs[b * REG_CAP + s] = r;
                                else {
                                    unsigned g = atomicAdd(gcnt, 1u);
                                    if (g < LCAP) list[g] = r;
                                }
                            }
                        }
                    }
                }
            }
        }

        __syncthreads();
        if (tid == 0) counts[b] = min(scnt, REG_CAP);

        // unpack + plain-store owned tile (tile grid partitions the volume)
        for (int i = tid; i < TZ * TY * OS; i += 512) {
            int row = i >> 7;
            int c   = i & 127;
            unsigned long long cell = sh[(row << 7) | swzq(c)];
            float v = (float)(int)(cell >> 32) * INV_FIX;
            float m = (float)(int)(unsigned)cell * INV_FIX;
            int uz = row >> 2, uy = row & 3;
            int o = ((z0 + uz) << 14) + ((y0 + uy) << 7) + c;
            out[o]       = v;
            out[OS3 + o] = m;
        }
    } else {
        // ---------------- plane role: quarter-plane, 2 z-slabs ----------------
        const int pb = b - GBLK;
        const int g  = pb >> 2;           // z-group: slabs 128+2g, 129+2g
        const int q  = pb & 3;            // y-quarter
        const int ybase = q << 5;
        const int rlo = max(0, ybase - 5);
        const int rhi = min(OS, ybase + 32 + 5);

        #pragma unroll
        for (int s = 0; s < (32 * OS) / 512; ++s)
            sh[tid + s * 512] = 0ull;
        __syncthreads();

        const int wq = tid & 31;
        const int rs = tid >> 5;          // 0..15

        for (int s = 0; s < PSPB; ++s) {
            int z = ZSPLIT + g * PSPB + s;
            for (int rb = 0; rb < 3; ++rb) {
                int r = rlo + rb * 16 + rs;
                bool valid = r < rhi;
                int rc = min(r, OS - 1);
                int idx4 = (((z << 14) + (rc << 7)) >> 2) + wq;
                float4 vfz = fz4[idx4];
                float4 vfy = fy4[idx4];
                float4 vfx = fx4[idx4];
                float4 vm  = m4p[idx4];
                float4 vx  = x4p[idx4];
                if (!valid) continue;
                bool homeRow = ((r >> 5) == q);

                #pragma unroll
                for (int p = 0; p < 4; ++p) {
                    int w = wq * 4 + p;
                    float gz = ((float*)&vfz)[p] + (float)z;
                    float gy = ((float*)&vfy)[p] + (float)r;
                    float gx = ((float*)&vfx)[p] + (float)w;
                    float m  = ((float*)&vm)[p];
                    float v  = ((float*)&vx)[p] * m;

                    float fyf = floorf(gy), fxf = floorf(gx);
                    float ffy = gy - fyf, ffx = gx - fxf;
                    int iy0 = (int)fyf, ix0 = (int)fxf;
                    int cy0 = min(max(iy0,     0), OS - 1);
                    int cy1 = min(max(iy0 + 1, 0), OS - 1);
                    int cx0 = min(max(ix0,     0), OS - 1);
                    int cx1 = min(max(ix0 + 1, 0), OS - 1);
                    int sx0 = swzq(cx0), sx1 = swzq(cx1);

                    if (gz >= (float)(OS - 1)) {   // both z-corners clamp to 127
                        float wy0 = 1.0f - ffy, wy1 = ffy;
                        float wx0 = 1.0f - ffx, wx1 = ffx;

                        int u0 = cy0 - ybase;
                        bool n0 = (cy0 - r <= 5) && (r - cy0 <= 5);
                        if (n0 && (unsigned)u0 < 32u) {
                            unsigned long long* row = &sh[u0 << 7];
                            atomicAdd(&row[sx0], pack2(v * wy0 * wx0, m * wy0 * wx0));
                            atomicAdd(&row[sx1], pack2(v * wy0 * wx1, m * wy0 * wx1));
                        }
                        int u1 = cy1 - ybase;
                        bool n1 = (cy1 - r <= 5) && (r - cy1 <= 5);
                        if (n1 && (unsigned)u1 < 32u) {
                            unsigned long long* row = &sh[u1 << 7];
                            atomicAdd(&row[sx0], pack2(v * wy1 * wx0, m * wy1 * wx0));
                            atomicAdd(&row[sx1], pack2(v * wy1 * wx1, m * wy1 * wx1));
                        }
                        if (homeRow && (!n0 || !n1)) {   // far-y (~never)
                            const int pbase = (OS - 1) << 14;
                            #pragma unroll
                            for (int e2 = 0; e2 < 2; ++e2) {
                                bool far = e2 ? !n1 : !n0;
                                if (!far) continue;
                                int cy = e2 ? cy1 : cy0;
                                float wy = e2 ? wy1 : wy0;
                                unsigned base = atomicAdd(gcnt, 2u);
                                #pragma unroll
                                for (int f2 = 0; f2 < 2; ++f2) {
                                    unsigned slt = base + f2;
                                    if (slt < LCAP) {
                                        float wgt = wy * (f2 ? wx1 : wx0);
                                        int4 qq;
                                        qq.x = pbase + (cy << 7) + (f2 ? cx1 : cx0);
                                        qq.y = __float_as_int(v * wgt);
                                        qq.z = __float_as_int(m * wgt);
                                        qq.w = 0;
                                        list[slt] = qq;
                                    }
                                }
                            }
                        }
                    } else if (homeRow) {
                        // rare boundary (z~128 with big negative flow_z): 8 records
                        float fzf = floorf(gz);
                        float ffz = gz - fzf;
                        int iz0 = (int)fzf;
                        unsigned base = atomicAdd(gcnt, 8u);
                        int t = 0;
                        #pragma unroll
                        for (int d2 = 0; d2 < 2; ++d2) {
                            int cz = min(max(iz0 + d2, 0), OS - 1);
                            float wz = d2 ? ffz : 1.0f - ffz;
                            #pragma unroll
                            for (int e2 = 0; e2 < 2; ++e2) {
                                int cy = e2 ? cy1 : cy0;
                                float wzy = wz * (e2 ? ffy : 1.0f - ffy);
                                #pragma unroll
                                for (int f2 = 0; f2 < 2; ++f2) {
                                    int cx = f2 ? cx1 : cx0;
                                    float wgt = wzy * (f2 ? ffx : 1.0f - ffx);
                                    unsigned slt = base + t;
                                    if (slt < LCAP) {
                                        int4 qq;
                                        qq.x = (cz << 14) + (cy << 7) + cx;
                                        qq.y = __float_as_int(v * wgt);
                                        qq.z = __float_as_int(m * wgt);
                                        qq.w = 0;
                                        list[slt] = qq;
                                    }
                                    ++t;
                                }
                            }
                        }
                    }
                }
            }
        }

        __syncthreads();

        // unpack + store quarter-plane partials (both channels)
        float* dst0 = partials + (size_t)g * 2 * PLANE_CELLS;
        float* dst1 = dst0 + PLANE_CELLS;
        for (int i = tid; i < 32 * OS; i += 512) {
            int row = i >> 7, c = i & 127;
            unsigned long long cell = sh[(row << 7) | swzq(c)];
            float v = (float)(int)(cell >> 32) * INV_FIX;
            float m = (float)(int)(unsigned)cell * INV_FIX;
            int o = ((ybase + row) << 7) + c;
            dst0[o] = v;
            dst1[o] = m;
        }
    }
}

// ---- K2: plane partial reduction, stage 1: 128 -> 16 slices ----
__global__ __launch_bounds__(256) void plane_reduce1(
    const float4* __restrict__ partials, float4* __restrict__ tmp)
{
    int t = blockIdx.x * 256 + threadIdx.x;        // 0..131071
    int slice = t >> 13;
    int rem = t & 8191;
    int ch = rem >> 12;
    int c4 = rem & 4095;
    float4 s = make_float4(0, 0, 0, 0);
    #pragma unroll
    for (int g = 0; g < PGROUPS / SLICES; ++g) {
        float4 v = partials[((size_t)((slice * (PGROUPS / SLICES) + g) * 2 + ch)) * 4096 + c4];
        s.x += v.x; s.y += v.y; s.z += v.z; s.w += v.w;
    }
    tmp[(size_t)(slice * 2 + ch) * 4096 + c4] = s;
}

// ---- K3: fused stage-2 reduce (atomic +=) + overflow-record apply ----
__global__ __launch_bounds__(256) void finalize(
    float* __restrict__ out, const float4* __restrict__ tmp,
    const unsigned* __restrict__ gcnt, const int* __restrict__ counts,
    const int4* __restrict__ regs, const int4* __restrict__ list)
{
    int b = blockIdx.x;
    if (b < 32) {
        int t = b * 256 + threadIdx.x;             // 0..8191
        int ch = t >> 12;
        int c4 = t & 4095;
        float4 s = make_float4(0, 0, 0, 0);
        #pragma unroll
        for (int sl = 0; sl < SLICES; ++sl) {
            float4 v = tmp[(size_t)(sl * 2 + ch) * 4096 + c4];
            s.x += v.x; s.y += v.y; s.z += v.z; s.w += v.w;
        }
        float* base = out + ch * OS3 + ((OS - 1) << 14) + c4 * 4;
        atomAddF(base + 0, s.x);
        atomAddF(base + 1, s.y);
        atomAddF(base + 2, s.z);
        atomAddF(base + 3, s.w);
    } else if (b < 32 + GBLK) {
        int rb = b - 32;
        int n = counts[rb];
        const int4* r = regs + (size_t)rb * REG_CAP;
        for (int i = threadIdx.x; i < n; i += 256) {
            int4 q = r[i];
            atomAddF(out + q.x,       __int_as_float(q.y));
            atomAddF(out + OS3 + q.x, __int_as_float(q.z));
        }
    } else {
        unsigned n = *gcnt;
        if (n > LCAP) n = LCAP;
        for (unsigned i = (unsigned)(b - 32 - GBLK) * 256 + threadIdx.x;
             i < n; i += 8 * 256) {
            int4 q = list[i];
            atomAddF(out + q.x,       __int_as_float(q.y));
            atomAddF(out + OS3 + q.x, __int_as_float(q.z));
        }
    }
}

// ---------------- fallback (ws too small): naive merged scatter ------------
__global__ __launch_bounds__(256) void warp_push_naive(
    const float* __restrict__ x, const float* __restrict__ flow,
    const float* __restrict__ mask, float* __restrict__ out, int N)
{
    int idx = blockIdx.x * blockDim.x + threadIdx.x;
    if (idx >= N) return;
    int w = idx & 127, h = (idx >> 7) & 127, z = idx >> 14;
    float gz = flow[idx] + (float)z;
    float gy = flow[N + idx] + (float)h;
    float gx = flow[2 * N + idx] + (float)w;
    float m = mask[idx];
    float v0 = x[idx] * m;
    float fz0 = floorf(gz), fy0 = floorf(gy), fx0 = floorf(gx);
    float fz = gz - fz0, fy = gy - fy0, fx = gx - fx0;
    int iz0 = (int)fz0, iy0 = (int)fy0, ix0 = (int)fx0;
    #pragma unroll
    for (int dz = 0; dz < 2; ++dz) {
        int cz = min(max(iz0 + dz, 0), OS - 1);
        float wz = dz ? fz : 1.0f - fz;
        #pragma unroll
        for (int dy = 0; dy < 2; ++dy) {
            int cy = min(max(iy0 + dy, 0), OS - 1);
            float wzy = wz * (dy ? fy : 1.0f - fy);
            #pragma unroll
            for (int dx = 0; dx < 2; ++dx) {
                int cx = min(max(ix0 + dx, 0), OS - 1);
                float wgt = wzy * (dx ? fx : 1.0f - fx);
                int o = (cz << 14) + (cy << 7) + cx;
                atomAddF(out + o,       v0 * wgt);
                atomAddF(out + OS3 + o, m * wgt);
            }
        }
    }
}

extern "C" void kernel_launch(void* const* d_in, const int* in_sizes, int n_in,
                              void* d_out, int out_size, void* d_ws, size_t ws_size,
                              hipStream_t stream) {
    (void)in_sizes; (void)n_in; (void)out_size;
    const float* x    = (const float*)d_in[0];
    const float* flow = (const float*)d_in[1];
    const float* mask = (const float*)d_in[2];
    float* out = (float*)d_out;

    if (ws_size >= (size_t)WS_NEED) {
        char* wsb = (char*)d_ws;
        unsigned* gcnt = (unsigned*)(wsb + OFF_CNT);
        int* counts    = (int*)(wsb + OFF_COUNTS);
        int4* regs     = (int4*)(wsb + OFF_REGS);
        int4* list     = (int4*)(wsb + OFF_LIST);
        float4* tmp    = (float4*)(wsb + OFF_TMP);
        float* parts   = (float*)(wsb + OFF_PART);

        hipMemsetAsync(d_ws, 0, 64, stream);   // zero list counter

        warp_fused<<<GBLK + PBLK, 512, 0, stream>>>(
            x, flow, mask, out, parts, gcnt, counts, regs, list);
        plane_reduce1<<<512, 256, 0, stream>>>((const float4*)parts, tmp);
        finalize<<<32 + GBLK + 8, 256, 0, stream>>>(
            out, (const float4*)tmp, gcnt, counts, regs, list);
    } else {
        hipMemsetAsync(d_out, 0, (size_t)2 * OS3 * sizeof(float), stream);
        warp_push_naive<<<NSRC / 256, 256, 0, stream>>>(x, flow, mask, out, NSRC);
    }
}

// Round 10
// 192.838 us; speedup vs baseline: 2.5109x; 1.0658x over previous
//
#include <hip/hip_runtime.h>

// WarpingLayer_3stacks: trilinear scatter-splat (grid_push) of
// intensities = [x*mask, mask] into 128^3, coords = flow + meshgrid.
// Input 384x128x128 f32. Output [1,2,128,128,128] f32.
//
// R1: global f32 atomicAdd is the wall -> privatize in LDS.
// R3-R6: structure-invariant ~187us => LDS atomic throughput is the pipe.
// R7/R8: pack both channels in one u64 (ds_add_u64, 32.18 fixed point) -> 247.
// R9: fuse gather+plane in one kernel (co-schedules VALU vs atomic pipes,
//     VALUBusy 16->64%) -> 206us; K1=85us now ~VALU/scan-bound.
// R10: TZ 4->8 (scan amp 6.25->4.375x, 512+512=1024 blocks = exactly 4/CU),
//      prescaled truncating fixed-point pack (-2 rndne/corner),
//      reduce1 folded into finalize (3 dispatches).

#define OS    128
#define OS3   (OS * OS * OS)
#define SRC_D 384
#define SRC_H 128
#define SRC_W 128
#define NSRC  (SRC_D * SRC_H * SRC_W)
#define ZSPLIT 128
#define PLANE_CELLS (OS * OS)

// gather tiling: block owns out[z0:z0+8][y0:y0+4][0:128]
#define TZ 8
#define TY 4
#define HALO 3
#define NJOBS 140          // (TZ+6)=14 z-rows x (TY+6)=10 y-rows
#define GITER 9            // ceil(140/16)
#define GBLK  512          // 16 z-tiles x 32 y-tiles

// plane tiling: quarter-plane (32 rows) per block, 2 z-slabs per group
#define PGROUPS 128        // z-groups (2 slabs each)
#define PSPB    2
#define PBLK    (PGROUPS * 4)   // 512 plane blocks

#define REG_CAP 1024       // per-gather-block record region
#define LCAP    65536      // shared overflow list

// ws layout (bytes)
#define OFF_CNT    0
#define OFF_COUNTS 1024
#define OFF_REGS   8192
#define OFF_LIST   (OFF_REGS + GBLK * REG_CAP * 16)           //  8,396,800
#define OFF_PART   (16 * 1024 * 1024)
#define WS_NEED    (OFF_PART + PGROUPS * 2 * PLANE_CELLS * 4) // 32 MB

#define S_FIX   262144.0f            // 2^18
#define INV_FIX (1.0f / 262144.0f)

// pack prescaled (a = v*wgt*2^18, b = m*wgt*2^18) via truncating cvt.
// b >= 0 and cell sums << 2^31 so low field never carries into high field.
__device__ __forceinline__ unsigned long long packt(float a, float b) {
    int vi = (int)a;
    int mi = (int)b;
    return ((unsigned long long)(unsigned)vi << 32) | (unsigned long long)(unsigned)mi;
}

// u64-cell bank swizzle (involution): spreads stride-4 column access.
__device__ __forceinline__ int swzq(int c) { return c ^ ((c >> 4) & 7); }

__device__ __forceinline__ void atomAddF(float* p, float v) {
    unsafeAtomicAdd(p, v);
}

// =================== K1: fused gather (z<128) + plane (z>=128) =============
// grid.x = GBLK + PBLK = 1024, 512 threads, 32KB LDS -> exactly 4 blocks/CU.
__global__ __launch_bounds__(512) void warp_fused(
    const float* __restrict__ x, const float* __restrict__ flow,
    const float* __restrict__ mask, float* __restrict__ out,
    float* __restrict__ partials,
    unsigned* __restrict__ gcnt, int* __restrict__ counts,
    int4* __restrict__ regs, int4* __restrict__ list)
{
    __shared__ unsigned long long sh[4096];   // 32 KB
    __shared__ int scnt;

    const int tid = threadIdx.x;
    const int b = blockIdx.x;

    const float4* __restrict__ fz4 = (const float4*)flow;
    const float4* __restrict__ fy4 = (const float4*)(flow + NSRC);
    const float4* __restrict__ fx4 = (const float4*)(flow + 2 * NSRC);
    const float4* __restrict__ m4p = (const float4*)mask;
    const float4* __restrict__ x4p = (const float4*)x;

    if (b < GBLK) {
        // ---------------- gather role ----------------
        if (tid == 0) scnt = 0;
        #pragma unroll
        for (int s = 0; s < 4096 / 512; ++s)
            sh[tid + s * 512] = 0ull;
        __syncthreads();

        const int z0 = (b & 15) * TZ;
        const int y0 = (b >> 4) * TY;
        const int wq = tid & 31;
        const int slot = tid >> 5;

        for (int it = 0; it < GITER; ++it) {
            int j = it * 16 + slot;
            int dz = j / 10, dyy = j - dz * 10;
            int zzr = z0 - HALO + dz;
            int hhr = y0 - HALO + dyy;
            int zz = min(max(zzr, 0), ZSPLIT - 1);
            int hh = min(max(hhr, 0), OS - 1);
            bool vrow = (j < NJOBS) && (zzr >= 0) && (zzr < ZSPLIT) &&
                        (hhr >= 0) && (hhr < OS);
            bool home = vrow && (zzr >= z0) && (zzr < z0 + TZ) &&
                        (hhr >= y0) && (hhr < y0 + TY);

            int idx4 = (((zz << 14) + (hh << 7)) >> 2) + wq;
            float4 vfz = fz4[idx4];       // unconditional clamped-address loads
            float4 vfy = fy4[idx4];
            float4 vfx = fx4[idx4];
            float4 vm  = m4p[idx4];
            float4 vx  = x4p[idx4];

            if (!vrow) continue;

            #pragma unroll
            for (int p = 0; p < 4; ++p) {
                float gz = ((float*)&vfz)[p] + (float)zz;
                float gy = ((float*)&vfy)[p] + (float)hh;
                float fzf = floorf(gz), fyf = floorf(gy);
                float ffz = gz - fzf, ffy = gy - fyf;
                int iz0 = (int)fzf, iy0 = (int)fyf;

                int cz0 = min(max(iz0,     0), OS - 1);
                int cz1 = min(max(iz0 + 1, 0), OS - 1);
                int cy0 = min(max(iy0,     0), OS - 1);
                int cy1 = min(max(iy0 + 1, 0), OS - 1);

                bool zin = (cz1 >= z0) && (cz0 < z0 + TZ);
                bool yin = (cy1 >= y0) && (cy0 < y0 + TY);
                if (!home && !(zin && yin)) continue;

                int w = wq * 4 + p;
                float gx = ((float*)&vfx)[p] + (float)w;
                float fxf = floorf(gx);
                float ffx = gx - fxf;
                int ix0 = (int)fxf;
                int cx0 = min(max(ix0,     0), OS - 1);
                int cx1 = min(max(ix0 + 1, 0), OS - 1);

                float m = ((float*)&vm)[p];
                float v = ((float*)&vx)[p] * m;
                float v_s = v * S_FIX;      // prescaled fixed-point inputs
                float m_s = m * S_FIX;

                #pragma unroll
                for (int d2 = 0; d2 < 2; ++d2) {
                    int cz = d2 ? cz1 : cz0;
                    float wz = d2 ? ffz : 1.0f - ffz;
                    bool nz = (cz - zz <= HALO) && (zz - cz <= HALO);
                    int uz = cz - z0;
                    #pragma unroll
                    for (int e2 = 0; e2 < 2; ++e2) {
                        int cy = e2 ? cy1 : cy0;
                        float wzy = wz * (e2 ? ffy : 1.0f - ffy);
                        bool ny = (cy - hh <= HALO) && (hh - cy <= HALO);
                        int uy = cy - y0;
                        bool nearc = nz && ny;
                        #pragma unroll
                        for (int f2 = 0; f2 < 2; ++f2) {
                            int cx = f2 ? cx1 : cx0;
                            float wgt = wzy * (f2 ? ffx : 1.0f - ffx);
                            if (nearc) {
                                if ((unsigned)uz < TZ && (unsigned)uy < TY) {
                                    int off = ((uz * TY + uy) << 7) + swzq(cx);
                                    atomicAdd(&sh[off], packt(v_s * wgt, m_s * wgt));
                                }
                            } else if (home) {
                                int4 r;
                                r.x = (cz << 14) + (cy << 7) + cx;
                                r.y = __float_as_int(v * wgt);
                                r.z = __float_as_int(m * wgt);
                                r.w = 0;
                                int s = atomicAdd(&scnt, 1);
                                if (s < REG_CAP) regs[b * REG_CAP + s] = r;
                                else {
                                    unsigned g = atomicAdd(gcnt, 1u);
                                    if (g < LCAP) list[g] = r;
                                }
                            }
                        }
                    }
                }
            }
        }

        __syncthreads();
        if (tid == 0) counts[b] = min(scnt, REG_CAP);

        // unpack + plain-store owned tile (tile grid partitions the volume)
        for (int i = tid; i < TZ * TY * OS; i += 512) {
            int row = i >> 7;              // uz*TY + uy, 0..31
            int c   = i & 127;
            unsigned long long cell = sh[(row << 7) | swzq(c)];
            float v = (float)(int)(cell >> 32) * INV_FIX;
            float m = (float)(int)(unsigned)cell * INV_FIX;
            int uz = row >> 2, uy = row & 3;
            int o = ((z0 + uz) << 14) + ((y0 + uy) << 7) + c;
            out[o]       = v;
            out[OS3 + o] = m;
        }
    } else {
        // ---------------- plane role: quarter-plane, 2 z-slabs ----------------
        const int pb = b - GBLK;
        const int g  = pb >> 2;           // z-group: slabs 128+2g, 129+2g
        const int q  = pb & 3;            // y-quarter
        const int ybase = q << 5;
        const int rlo = max(0, ybase - 5);
        const int rhi = min(OS, ybase + 32 + 5);

        #pragma unroll
        for (int s = 0; s < 4096 / 512; ++s)
            sh[tid + s * 512] = 0ull;
        __syncthreads();

        const int wq = tid & 31;
        const int rs = tid >> 5;          // 0..15

        for (int s = 0; s < PSPB; ++s) {
            int z = ZSPLIT + g * PSPB + s;
            for (int rb = 0; rb < 3; ++rb) {
                int r = rlo + rb * 16 + rs;
                bool valid = r < rhi;
                int rc = min(r, OS - 1);
                int idx4 = (((z << 14) + (rc << 7)) >> 2) + wq;
                float4 vfz = fz4[idx4];
                float4 vfy = fy4[idx4];
                float4 vfx = fx4[idx4];
                float4 vm  = m4p[idx4];
                float4 vx  = x4p[idx4];
                if (!valid) continue;
                bool homeRow = ((r >> 5) == q);

                #pragma unroll
                for (int p = 0; p < 4; ++p) {
                    int w = wq * 4 + p;
                    float gz = ((float*)&vfz)[p] + (float)z;
                    float gy = ((float*)&vfy)[p] + (float)r;
                    float gx = ((float*)&vfx)[p] + (float)w;
                    float m  = ((float*)&vm)[p];
                    float v  = ((float*)&vx)[p] * m;

                    float fyf = floorf(gy), fxf = floorf(gx);
                    float ffy = gy - fyf, ffx = gx - fxf;
                    int iy0 = (int)fyf, ix0 = (int)fxf;
                    int cy0 = min(max(iy0,     0), OS - 1);
                    int cy1 = min(max(iy0 + 1, 0), OS - 1);
                    int cx0 = min(max(ix0,     0), OS - 1);
                    int cx1 = min(max(ix0 + 1, 0), OS - 1);
                    int sx0 = swzq(cx0), sx1 = swzq(cx1);

                    if (gz >= (float)(OS - 1)) {   // both z-corners clamp to 127
                        float wy0 = 1.0f - ffy, wy1 = ffy;
                        float wx0 = 1.0f - ffx, wx1 = ffx;
                        float v_s = v * S_FIX;
                        float m_s = m * S_FIX;

                        int u0 = cy0 - ybase;
                        bool n0 = (cy0 - r <= 5) && (r - cy0 <= 5);
                        if (n0 && (unsigned)u0 < 32u) {
                            unsigned long long* row = &sh[u0 << 7];
                            float a = v_s * wy0, bb = m_s * wy0;
                            atomicAdd(&row[sx0], packt(a * wx0, bb * wx0));
                            atomicAdd(&row[sx1], packt(a * wx1, bb * wx1));
                        }
                        int u1 = cy1 - ybase;
                        bool n1 = (cy1 - r <= 5) && (r - cy1 <= 5);
                        if (n1 && (unsigned)u1 < 32u) {
                            unsigned long long* row = &sh[u1 << 7];
                            float a = v_s * wy1, bb = m_s * wy1;
                            atomicAdd(&row[sx0], packt(a * wx0, bb * wx0));
                            atomicAdd(&row[sx1], packt(a * wx1, bb * wx1));
                        }
                        if (homeRow && (!n0 || !n1)) {   // far-y (~never)
                            const int pbase = (OS - 1) << 14;
                            #pragma unroll
                            for (int e2 = 0; e2 < 2; ++e2) {
                                bool far = e2 ? !n1 : !n0;
                                if (!far) continue;
                                int cy = e2 ? cy1 : cy0;
                                float wy = e2 ? wy1 : wy0;
                                unsigned base = atomicAdd(gcnt, 2u);
                                #pragma unroll
                                for (int f2 = 0; f2 < 2; ++f2) {
                                    unsigned slt = base + f2;
                                    if (slt < LCAP) {
                                        float wgt = wy * (f2 ? wx1 : wx0);
                                        int4 qq;
                                        qq.x = pbase + (cy << 7) + (f2 ? cx1 : cx0);
                                        qq.y = __float_as_int(v * wgt);
                                        qq.z = __float_as_int(m * wgt);
                                        qq.w = 0;
                                        list[slt] = qq;
                                    }
                                }
                            }
                        }
                    } else if (homeRow) {
                        // rare boundary (z~128 with big negative flow_z): 8 records
                        float fzf = floorf(gz);
                        float ffz = gz - fzf;
                        int iz0 = (int)fzf;
                        unsigned base = atomicAdd(gcnt, 8u);
                        int t = 0;
                        #pragma unroll
                        for (int d2 = 0; d2 < 2; ++d2) {
                            int cz = min(max(iz0 + d2, 0), OS - 1);
                            float wz = d2 ? ffz : 1.0f - ffz;
                            #pragma unroll
                            for (int e2 = 0; e2 < 2; ++e2) {
                                int cy = e2 ? cy1 : cy0;
                                float wzy = wz * (e2 ? ffy : 1.0f - ffy);
                                #pragma unroll
                                for (int f2 = 0; f2 < 2; ++f2) {
                                    int cx = f2 ? cx1 : cx0;
                                    float wgt = wzy * (f2 ? ffx : 1.0f - ffx);
                                    unsigned slt = base + t;
                                    if (slt < LCAP) {
                                        int4 qq;
                                        qq.x = (cz << 14) + (cy << 7) + cx;
                                        qq.y = __float_as_int(v * wgt);
                                        qq.z = __float_as_int(m * wgt);
                                        qq.w = 0;
                                        list[slt] = qq;
                                    }
                                    ++t;
                                }
                            }
                        }
                    }
                }
            }
        }

        __syncthreads();

        // unpack + store quarter-plane partials (both channels)
        float* dst0 = partials + (size_t)g * 2 * PLANE_CELLS;
        float* dst1 = dst0 + PLANE_CELLS;
        for (int i = tid; i < 32 * OS; i += 512) {
            int row = i >> 7, c = i & 127;
            unsigned long long cell = sh[(row << 7) | swzq(c)];
            float v = (float)(int)(cell >> 32) * INV_FIX;
            float m = (float)(int)(unsigned)cell * INV_FIX;
            int o = ((ybase + row) << 7) + c;
            dst0[o] = v;
            dst1[o] = m;
        }
    }
}

// ---- K2: fused full plane reduction (128 deep) + overflow-record apply ----
#define RBLK 128    // reduction blocks: 128 x 256 = 32768 cells (2ch x 16384)
__global__ __launch_bounds__(256) void finalize(
    float* __restrict__ out, const float* __restrict__ partials,
    const unsigned* __restrict__ gcnt, const int* __restrict__ counts,
    const int4* __restrict__ regs, const int4* __restrict__ list)
{
    int b = blockIdx.x;
    if (b < RBLK) {
        int t = b * 256 + threadIdx.x;            // 0..32767
        int ch   = t >> 14;
        int cell = t & 16383;
        const float* p = partials + (size_t)ch * PLANE_CELLS + cell;
        float s = 0.0f;
        #pragma unroll 8
        for (int g = 0; g < PGROUPS; ++g)
            s += p[(size_t)g * 2 * PLANE_CELLS];
        atomAddF(out + ch * OS3 + ((OS - 1) << 14) + cell, s);
    } else if (b < RBLK + GBLK) {
        int rb = b - RBLK;
        int n = counts[rb];
        const int4* r = regs + (size_t)rb * REG_CAP;
        for (int i = threadIdx.x; i < n; i += 256) {
            int4 q = r[i];
            atomAddF(out + q.x,       __int_as_float(q.y));
            atomAddF(out + OS3 + q.x, __int_as_float(q.z));
        }
    } else {
        unsigned n = *gcnt;
        if (n > LCAP) n = LCAP;
        for (unsigned i = (unsigned)(b - RBLK - GBLK) * 256 + threadIdx.x;
             i < n; i += 8 * 256) {
            int4 q = list[i];
            atomAddF(out + q.x,       __int_as_float(q.y));
            atomAddF(out + OS3 + q.x, __int_as_float(q.z));
        }
    }
}

// ---------------- fallback (ws too small): naive merged scatter ------------
__global__ __launch_bounds__(256) void warp_push_naive(
    const float* __restrict__ x, const float* __restrict__ flow,
    const float* __restrict__ mask, float* __restrict__ out, int N)
{
    int idx = blockIdx.x * blockDim.x + threadIdx.x;
    if (idx >= N) return;
    int w = idx & 127, h = (idx >> 7) & 127, z = idx >> 14;
    float gz = flow[idx] + (float)z;
    float gy = flow[N + idx] + (float)h;
    float gx = flow[2 * N + idx] + (float)w;
    float m = mask[idx];
    float v0 = x[idx] * m;
    float fz0 = floorf(gz), fy0 = floorf(gy), fx0 = floorf(gx);
    float fz = gz - fz0, fy = gy - fy0, fx = gx - fx0;
    int iz0 = (int)fz0, iy0 = (int)fy0, ix0 = (int)fx0;
    #pragma unroll
    for (int dz = 0; dz < 2; ++dz) {
        int cz = min(max(iz0 + dz, 0), OS - 1);
        float wz = dz ? fz : 1.0f - fz;
        #pragma unroll
        for (int dy = 0; dy < 2; ++dy) {
            int cy = min(max(iy0 + dy, 0), OS - 1);
            float wzy = wz * (dy ? fy : 1.0f - fy);
            #pragma unroll
            for (int dx = 0; dx < 2; ++dx) {
                int cx = min(max(ix0 + dx, 0), OS - 1);
                float wgt = wzy * (dx ? fx : 1.0f - fx);
                int o = (cz << 14) + (cy << 7) + cx;
                atomAddF(out + o,       v0 * wgt);
                atomAddF(out + OS3 + o, m * wgt);
            }
        }
    }
}

extern "C" void kernel_launch(void* const* d_in, const int* in_sizes, int n_in,
                              void* d_out, int out_size, void* d_ws, size_t ws_size,
                              hipStream_t stream) {
    (void)in_sizes; (void)n_in; (void)out_size;
    const float* x    = (const float*)d_in[0];
    const float* flow = (const float*)d_in[1];
    const float* mask = (const float*)d_in[2];
    float* out = (float*)d_out;

    if (ws_size >= (size_t)WS_NEED) {
        char* wsb = (char*)d_ws;
        unsigned* gcnt = (unsigned*)(wsb + OFF_CNT);
        int* counts    = (int*)(wsb + OFF_COUNTS);
        int4* regs     = (int4*)(wsb + OFF_REGS);
        int4* list     = (int4*)(wsb + OFF_LIST);
        float* parts   = (float*)(wsb + OFF_PART);

        hipMemsetAsync(d_ws, 0, 64, stream);   // zero list counter

        warp_fused<<<GBLK + PBLK, 512, 0, stream>>>(
            x, flow, mask, out, parts, gcnt, counts, regs, list);
        finalize<<<RBLK + GBLK + 8, 256, 0, stream>>>(
            out, parts, gcnt, counts, regs, list);
    } else {
        hipMemsetAsync(d_out, 0, (size_t)2 * OS3 * sizeof(float), stream);
        warp_push_naive<<<NSRC / 256, 256, 0, stream>>>(x, flow, mask, out, NSRC);
    }
}

// Round 11
// 190.727 us; speedup vs baseline: 2.5387x; 1.0111x over previous
//
#include <hip/hip_runtime.h>

// WarpingLayer_3stacks: trilinear scatter-splat (grid_push) of
// intensities = [x*mask, mask] into 128^3, coords = flow + meshgrid.
// Input 384x128x128 f32. Output [1,2,128,128,128] f32.
//
// R1: global f32 atomicAdd is the wall -> privatize in LDS.
// R3-R6: structure-invariant ~187us => LDS atomic throughput is the pipe.
// R7/R8: pack both channels in one u64 (ds_add_u64, 32.18 fixed pt) -> 247.
// R9: fuse gather+plane (co-schedule pipes) -> 206; R10: TZ=8 scan-amp cut
//     -> 193, K1=74us at 1.36 cy/lane-atomic (33.5M u64 atomics).
// R11: balance roles: plane PSPB 2->4 => 512 gather + 256 plane = 768 blocks
//     = exactly 3/CU; round-robin gives every CU {2 gather + 1 plane} =
//     identical 131K lane-atomics/CU (kills the gather-straggler tail).

#define OS    128
#define OS3   (OS * OS * OS)
#define SRC_D 384
#define SRC_H 128
#define SRC_W 128
#define NSRC  (SRC_D * SRC_H * SRC_W)
#define ZSPLIT 128
#define PLANE_CELLS (OS * OS)

// gather tiling: block owns out[z0:z0+8][y0:y0+4][0:128]
#define TZ 8
#define TY 4
#define HALO 3
#define NJOBS 140          // (TZ+6)=14 z-rows x (TY+6)=10 y-rows
#define GITER 9            // ceil(140/16)
#define GBLK  512          // 16 z-tiles x 32 y-tiles

// plane tiling: quarter-plane (32 rows) per block, 4 z-slabs per group
#define PGROUPS 64         // z-groups (4 slabs each)
#define PSPB    4
#define PBLK    (PGROUPS * 4)   // 256 plane blocks

#define REG_CAP 1024       // per-gather-block record region
#define LCAP    65536      // shared overflow list

// ws layout (bytes)
#define OFF_CNT    0
#define OFF_COUNTS 1024
#define OFF_REGS   8192
#define OFF_LIST   (OFF_REGS + GBLK * REG_CAP * 16)           //  8,396,800
#define OFF_PART   (16 * 1024 * 1024)
#define WS_NEED    (OFF_PART + PGROUPS * 2 * PLANE_CELLS * 4) // 24 MB

#define S_FIX   262144.0f            // 2^18
#define INV_FIX (1.0f / 262144.0f)

// pack prescaled (a = v*wgt*2^18, b = m*wgt*2^18) via truncating cvt.
// b >= 0 and cell sums << 2^31 so low field never carries into high field.
__device__ __forceinline__ unsigned long long packt(float a, float b) {
    int vi = (int)a;
    int mi = (int)b;
    return ((unsigned long long)(unsigned)vi << 32) | (unsigned long long)(unsigned)mi;
}

// u64-cell bank swizzle (involution): spreads stride-4 column access.
__device__ __forceinline__ int swzq(int c) { return c ^ ((c >> 4) & 7); }

__device__ __forceinline__ void atomAddF(float* p, float v) {
    unsafeAtomicAdd(p, v);
}

// =================== K1: fused gather (z<128) + plane (z>=128) =============
// grid.x = GBLK + PBLK = 768, 512 threads, 32KB LDS -> exactly 3 blocks/CU;
// round-robin dispatch => each CU holds 2 gather + 1 plane (balanced atomics).
__global__ __launch_bounds__(512) void warp_fused(
    const float* __restrict__ x, const float* __restrict__ flow,
    const float* __restrict__ mask, float* __restrict__ out,
    float* __restrict__ partials,
    unsigned* __restrict__ gcnt, int* __restrict__ counts,
    int4* __restrict__ regs, int4* __restrict__ list)
{
    __shared__ unsigned long long sh[4096];   // 32 KB
    __shared__ int scnt;

    const int tid = threadIdx.x;
    const int b = blockIdx.x;

    const float4* __restrict__ fz4 = (const float4*)flow;
    const float4* __restrict__ fy4 = (const float4*)(flow + NSRC);
    const float4* __restrict__ fx4 = (const float4*)(flow + 2 * NSRC);
    const float4* __restrict__ m4p = (const float4*)mask;
    const float4* __restrict__ x4p = (const float4*)x;

    if (b < GBLK) {
        // ---------------- gather role ----------------
        if (tid == 0) scnt = 0;
        #pragma unroll
        for (int s = 0; s < 4096 / 512; ++s)
            sh[tid + s * 512] = 0ull;
        __syncthreads();

        const int z0 = (b & 15) * TZ;
        const int y0 = (b >> 4) * TY;
        const int wq = tid & 31;
        const int slot = tid >> 5;

        for (int it = 0; it < GITER; ++it) {
            int j = it * 16 + slot;
            int dz = j / 10, dyy = j - dz * 10;
            int zzr = z0 - HALO + dz;
            int hhr = y0 - HALO + dyy;
            int zz = min(max(zzr, 0), ZSPLIT - 1);
            int hh = min(max(hhr, 0), OS - 1);
            bool vrow = (j < NJOBS) && (zzr >= 0) && (zzr < ZSPLIT) &&
                        (hhr >= 0) && (hhr < OS);
            bool home = vrow && (zzr >= z0) && (zzr < z0 + TZ) &&
                        (hhr >= y0) && (hhr < y0 + TY);

            int idx4 = (((zz << 14) + (hh << 7)) >> 2) + wq;
            float4 vfz = fz4[idx4];       // unconditional clamped-address loads
            float4 vfy = fy4[idx4];
            float4 vfx = fx4[idx4];
            float4 vm  = m4p[idx4];
            float4 vx  = x4p[idx4];

            if (!vrow) continue;

            #pragma unroll
            for (int p = 0; p < 4; ++p) {
                float gz = ((float*)&vfz)[p] + (float)zz;
                float gy = ((float*)&vfy)[p] + (float)hh;
                float fzf = floorf(gz), fyf = floorf(gy);
                float ffz = gz - fzf, ffy = gy - fyf;
                int iz0 = (int)fzf, iy0 = (int)fyf;

                int cz0 = min(max(iz0,     0), OS - 1);
                int cz1 = min(max(iz0 + 1, 0), OS - 1);
                int cy0 = min(max(iy0,     0), OS - 1);
                int cy1 = min(max(iy0 + 1, 0), OS - 1);

                bool zin = (cz1 >= z0) && (cz0 < z0 + TZ);
                bool yin = (cy1 >= y0) && (cy0 < y0 + TY);
                if (!home && !(zin && yin)) continue;

                int w = wq * 4 + p;
                float gx = ((float*)&vfx)[p] + (float)w;
                float fxf = floorf(gx);
                float ffx = gx - fxf;
                int ix0 = (int)fxf;
                int cx0 = min(max(ix0,     0), OS - 1);
                int cx1 = min(max(ix0 + 1, 0), OS - 1);

                float m = ((float*)&vm)[p];
                float v = ((float*)&vx)[p] * m;
                float v_s = v * S_FIX;      // prescaled fixed-point inputs
                float m_s = m * S_FIX;

                #pragma unroll
                for (int d2 = 0; d2 < 2; ++d2) {
                    int cz = d2 ? cz1 : cz0;
                    float wz = d2 ? ffz : 1.0f - ffz;
                    bool nz = (cz - zz <= HALO) && (zz - cz <= HALO);
                    int uz = cz - z0;
                    #pragma unroll
                    for (int e2 = 0; e2 < 2; ++e2) {
                        int cy = e2 ? cy1 : cy0;
                        float wzy = wz * (e2 ? ffy : 1.0f - ffy);
                        bool ny = (cy - hh <= HALO) && (hh - cy <= HALO);
                        int uy = cy - y0;
                        bool nearc = nz && ny;
                        #pragma unroll
                        for (int f2 = 0; f2 < 2; ++f2) {
                            int cx = f2 ? cx1 : cx0;
                            float wgt = wzy * (f2 ? ffx : 1.0f - ffx);
                            if (nearc) {
                                if ((unsigned)uz < TZ && (unsigned)uy < TY) {
                                    int off = ((uz * TY + uy) << 7) + swzq(cx);
                                    atomicAdd(&sh[off], packt(v_s * wgt, m_s * wgt));
                                }
                            } else if (home) {
                                int4 r;
                                r.x = (cz << 14) + (cy << 7) + cx;
                                r.y = __float_as_int(v * wgt);
                                r.z = __float_as_int(m * wgt);
                                r.w = 0;
                                int s = atomicAdd(&scnt, 1);
                                if (s < REG_CAP) regs[b * REG_CAP + s] = r;
                                else {
                                    unsigned g = atomicAdd(gcnt, 1u);
                                    if (g < LCAP) list[g] = r;
                                }
                            }
                        }
                    }
                }
            }
        }

        __syncthreads();
        if (tid == 0) counts[b] = min(scnt, REG_CAP);

        // unpack + plain-store owned tile (tile grid partitions the volume)
        for (int i = tid; i < TZ * TY * OS; i += 512) {
            int row = i >> 7;              // uz*TY + uy, 0..31
            int c   = i & 127;
            unsigned long long cell = sh[(row << 7) | swzq(c)];
            float v = (float)(int)(cell >> 32) * INV_FIX;
            float m = (float)(int)(unsigned)cell * INV_FIX;
            int uz = row >> 2, uy = row & 3;
            int o = ((z0 + uz) << 14) + ((y0 + uy) << 7) + c;
            out[o]       = v;
            out[OS3 + o] = m;
        }
    } else {
        // ---------------- plane role: quarter-plane, 4 z-slabs ----------------
        const int pb = b - GBLK;
        const int g  = pb >> 2;           // z-group: slabs 128+4g .. 131+4g
        const int q  = pb & 3;            // y-quarter
        const int ybase = q << 5;
        const int rlo = max(0, ybase - 5);
        const int rhi = min(OS, ybase + 32 + 5);

        #pragma unroll
        for (int s = 0; s < 4096 / 512; ++s)
            sh[tid + s * 512] = 0ull;
        __syncthreads();

        const int wq = tid & 31;
        const int rs = tid >> 5;          // 0..15

        for (int s = 0; s < PSPB; ++s) {
            int z = ZSPLIT + g * PSPB + s;
            for (int rb = 0; rb < 3; ++rb) {
                int r = rlo + rb * 16 + rs;
                bool valid = r < rhi;
                int rc = min(r, OS - 1);
                int idx4 = (((z << 14) + (rc << 7)) >> 2) + wq;
                float4 vfz = fz4[idx4];
                float4 vfy = fy4[idx4];
                float4 vfx = fx4[idx4];
                float4 vm  = m4p[idx4];
                float4 vx  = x4p[idx4];
                if (!valid) continue;
                bool homeRow = ((r >> 5) == q);

                #pragma unroll
                for (int p = 0; p < 4; ++p) {
                    int w = wq * 4 + p;
                    float gz = ((float*)&vfz)[p] + (float)z;
                    float gy = ((float*)&vfy)[p] + (float)r;
                    float gx = ((float*)&vfx)[p] + (float)w;
                    float m  = ((float*)&vm)[p];
                    float v  = ((float*)&vx)[p] * m;

                    float fyf = floorf(gy), fxf = floorf(gx);
                    float ffy = gy - fyf, ffx = gx - fxf;
                    int iy0 = (int)fyf, ix0 = (int)fxf;
                    int cy0 = min(max(iy0,     0), OS - 1);
                    int cy1 = min(max(iy0 + 1, 0), OS - 1);
                    int cx0 = min(max(ix0,     0), OS - 1);
                    int cx1 = min(max(ix0 + 1, 0), OS - 1);
                    int sx0 = swzq(cx0), sx1 = swzq(cx1);

                    if (gz >= (float)(OS - 1)) {   // both z-corners clamp to 127
                        float wy0 = 1.0f - ffy, wy1 = ffy;
                        float wx0 = 1.0f - ffx, wx1 = ffx;
                        float v_s = v * S_FIX;
                        float m_s = m * S_FIX;

                        int u0 = cy0 - ybase;
                        bool n0 = (cy0 - r <= 5) && (r - cy0 <= 5);
                        if (n0 && (unsigned)u0 < 32u) {
                            unsigned long long* row = &sh[u0 << 7];
                            float a = v_s * wy0, bb = m_s * wy0;
                            atomicAdd(&row[sx0], packt(a * wx0, bb * wx0));
                            atomicAdd(&row[sx1], packt(a * wx1, bb * wx1));
                        }
                        int u1 = cy1 - ybase;
                        bool n1 = (cy1 - r <= 5) && (r - cy1 <= 5);
                        if (n1 && (unsigned)u1 < 32u) {
                            unsigned long long* row = &sh[u1 << 7];
                            float a = v_s * wy1, bb = m_s * wy1;
                            atomicAdd(&row[sx0], packt(a * wx0, bb * wx0));
                            atomicAdd(&row[sx1], packt(a * wx1, bb * wx1));
                        }
                        if (homeRow && (!n0 || !n1)) {   // far-y (~never)
                            const int pbase = (OS - 1) << 14;
                            #pragma unroll
                            for (int e2 = 0; e2 < 2; ++e2) {
                                bool far = e2 ? !n1 : !n0;
                                if (!far) continue;
                                int cy = e2 ? cy1 : cy0;
                                float wy = e2 ? wy1 : wy0;
                                unsigned base = atomicAdd(gcnt, 2u);
                                #pragma unroll
                                for (int f2 = 0; f2 < 2; ++f2) {
                                    unsigned slt = base + f2;
                                    if (slt < LCAP) {
                                        float wgt = wy * (f2 ? wx1 : wx0);
                                        int4 qq;
                                        qq.x = pbase + (cy << 7) + (f2 ? cx1 : cx0);
                                        qq.y = __float_as_int(v * wgt);
                                        qq.z = __float_as_int(m * wgt);
                                        qq.w = 0;
                                        list[slt] = qq;
                                    }
                                }
                            }
                        }
                    } else if (homeRow) {
                        // rare boundary (z~128 with big negative flow_z): 8 records
                        float fzf = floorf(gz);
                        float ffz = gz - fzf;
                        int iz0 = (int)fzf;
                        unsigned base = atomicAdd(gcnt, 8u);
                        int t = 0;
                        #pragma unroll
                        for (int d2 = 0; d2 < 2; ++d2) {
                            int cz = min(max(iz0 + d2, 0), OS - 1);
                            float wz = d2 ? ffz : 1.0f - ffz;
                            #pragma unroll
                            for (int e2 = 0; e2 < 2; ++e2) {
                                int cy = e2 ? cy1 : cy0;
                                float wzy = wz * (e2 ? ffy : 1.0f - ffy);
                                #pragma unroll
                                for (int f2 = 0; f2 < 2; ++f2) {
                                    int cx = f2 ? cx1 : cx0;
                                    float wgt = wzy * (f2 ? ffx : 1.0f - ffx);
                                    unsigned slt = base + t;
                                    if (slt < LCAP) {
                                        int4 qq;
                                        qq.x = (cz << 14) + (cy << 7) + cx;
                                        qq.y = __float_as_int(v * wgt);
                                        qq.z = __float_as_int(m * wgt);
                                        qq.w = 0;
                                        list[slt] = qq;
                                    }
                                    ++t;
                                }
                            }
                        }
                    }
                }
            }
        }

        __syncthreads();

        // unpack + store quarter-plane partials (both channels)
        float* dst0 = partials + (size_t)g * 2 * PLANE_CELLS;
        float* dst1 = dst0 + PLANE_CELLS;
        for (int i = tid; i < 32 * OS; i += 512) {
            int row = i >> 7, c = i & 127;
            unsigned long long cell = sh[(row << 7) | swzq(c)];
            float v = (float)(int)(cell >> 32) * INV_FIX;
            float m = (float)(int)(unsigned)cell * INV_FIX;
            int o = ((ybase + row) << 7) + c;
            dst0[o] = v;
            dst1[o] = m;
        }
    }
}

// ---- K2: fused full plane reduction (64 deep) + overflow-record apply ----
#define RBLK 128    // reduction blocks: 128 x 256 = 32768 cells (2ch x 16384)
__global__ __launch_bounds__(256) void finalize(
    float* __restrict__ out, const float* __restrict__ partials,
    const unsigned* __restrict__ gcnt, const int* __restrict__ counts,
    const int4* __restrict__ regs, const int4* __restrict__ list)
{
    int b = blockIdx.x;
    if (b < RBLK) {
        int t = b * 256 + threadIdx.x;            // 0..32767
        int ch   = t >> 14;
        int cell = t & 16383;
        const float* p = partials + (size_t)ch * PLANE_CELLS + cell;
        float s = 0.0f;
        #pragma unroll 8
        for (int g = 0; g < PGROUPS; ++g)
            s += p[(size_t)g * 2 * PLANE_CELLS];
        atomAddF(out + ch * OS3 + ((OS - 1) << 14) + cell, s);
    } else if (b < RBLK + GBLK) {
        int rb = b - RBLK;
        int n = counts[rb];
        const int4* r = regs + (size_t)rb * REG_CAP;
        for (int i = threadIdx.x; i < n; i += 256) {
            int4 q = r[i];
            atomAddF(out + q.x,       __int_as_float(q.y));
            atomAddF(out + OS3 + q.x, __int_as_float(q.z));
        }
    } else {
        unsigned n = *gcnt;
        if (n > LCAP) n = LCAP;
        for (unsigned i = (unsigned)(b - RBLK - GBLK) * 256 + threadIdx.x;
             i < n; i += 8 * 256) {
            int4 q = list[i];
            atomAddF(out + q.x,       __int_as_float(q.y));
            atomAddF(out + OS3 + q.x, __int_as_float(q.z));
        }
    }
}

// ---------------- fallback (ws too small): naive merged scatter ------------
__global__ __launch_bounds__(256) void warp_push_naive(
    const float* __restrict__ x, const float* __restrict__ flow,
    const float* __restrict__ mask, float* __restrict__ out, int N)
{
    int idx = blockIdx.x * blockDim.x + threadIdx.x;
    if (idx >= N) return;
    int w = idx & 127, h = (idx >> 7) & 127, z = idx >> 14;
    float gz = flow[idx] + (float)z;
    float gy = flow[N + idx] + (float)h;
    float gx = flow[2 * N + idx] + (float)w;
    float m = mask[idx];
    float v0 = x[idx] * m;
    float fz0 = floorf(gz), fy0 = floorf(gy), fx0 = floorf(gx);
    float fz = gz - fz0, fy = gy - fy0, fx = gx - fx0;
    int iz0 = (int)fz0, iy0 = (int)fy0, ix0 = (int)fx0;
    #pragma unroll
    for (int dz = 0; dz < 2; ++dz) {
        int cz = min(max(iz0 + dz, 0), OS - 1);
        float wz = dz ? fz : 1.0f - fz;
        #pragma unroll
        for (int dy = 0; dy < 2; ++dy) {
            int cy = min(max(iy0 + dy, 0), OS - 1);
            float wzy = wz * (dy ? fy : 1.0f - fy);
            #pragma unroll
            for (int dx = 0; dx < 2; ++dx) {
                int cx = min(max(ix0 + dx, 0), OS - 1);
                float wgt = wzy * (dx ? fx : 1.0f - fx);
                int o = (cz << 14) + (cy << 7) + cx;
                atomAddF(out + o,       v0 * wgt);
                atomAddF(out + OS3 + o, m * wgt);
            }
        }
    }
}

extern "C" void kernel_launch(void* const* d_in, const int* in_sizes, int n_in,
                              void* d_out, int out_size, void* d_ws, size_t ws_size,
                              hipStream_t stream) {
    (void)in_sizes; (void)n_in; (void)out_size;
    const float* x    = (const float*)d_in[0];
    const float* flow = (const float*)d_in[1];
    const float* mask = (const float*)d_in[2];
    float* out = (float*)d_out;

    if (ws_size >= (size_t)WS_NEED) {
        char* wsb = (char*)d_ws;
        unsigned* gcnt = (unsigned*)(wsb + OFF_CNT);
        int* counts    = (int*)(wsb + OFF_COUNTS);
        int4* regs     = (int4*)(wsb + OFF_REGS);
        int4* list     = (int4*)(wsb + OFF_LIST);
        float* parts   = (float*)(wsb + OFF_PART);

        hipMemsetAsync(d_ws, 0, 64, stream);   // zero list counter

        warp_fused<<<GBLK + PBLK, 512, 0, stream>>>(
            x, flow, mask, out, parts, gcnt, counts, regs, list);
        finalize<<<RBLK + GBLK + 8, 256, 0, stream>>>(
            out, parts, gcnt, counts, regs, list);
    } else {
        hipMemsetAsync(d_out, 0, (size_t)2 * OS3 * sizeof(float), stream);
        warp_push_naive<<<NSRC / 256, 256, 0, stream>>>(x, flow, mask, out, NSRC);
    }
}